// Round 1
// 1525.972 us; speedup vs baseline: 1.8708x; 1.8708x over previous
//
#include <hip/hip_runtime.h>
#include <math.h>

typedef __bf16 bf16;
typedef bf16 bf16x8 __attribute__((ext_vector_type(8)));
typedef float f32x4 __attribute__((ext_vector_type(4)));
typedef unsigned int uint32;

#define B_   2
#define S_   2048
#define H_   2048
#define NH_  16
#define NKV_ 4
#define HD_  128
#define I_   8192
#define M_   (B_ * S_)   // 4096 token rows

// ---------------------------------------------------------------------------
// async global->LDS, 16B per lane. Dest is wave-uniform base + lane*16.
// ---------------------------------------------------------------------------
typedef __attribute__((address_space(3))) void       lds_void;
typedef __attribute__((address_space(1))) const void gbl_void;

__device__ __forceinline__ void async16(const void* g, void* l) {
  __builtin_amdgcn_global_load_lds((gbl_void*)g, (lds_void*)l, 16, 0, 0);
}

// ---------------------------------------------------------------------------
// Dtype probe: raw inputs fp32 vs bf16 (verified: fp32 on this harness).
// ---------------------------------------------------------------------------
__global__ void probe_k(const uint32* __restrict__ x, int* __restrict__ flag) {
  const int lane = threadIdx.x;
  const uint32 u = x[lane];
  float blo = fabsf(__uint_as_float(u << 16));
  float bhi = fabsf(__uint_as_float(u & 0xffff0000u));
  float fv  = fabsf(__uint_as_float(u));
  if (!(blo < 1e30f)) blo = 3e38f;
  if (!(bhi < 1e30f)) bhi = 3e38f;
  if (!(fv  < 1e30f)) fv  = 3e38f;
  float mb = fmaxf(blo, bhi);
  float mf = fv;
#pragma unroll
  for (int off = 1; off < 64; off <<= 1) {
    mb = fmaxf(mb, __shfl_xor(mb, off, 64));
    mf = fmaxf(mf, __shfl_xor(mf, off, 64));
  }
  if (lane == 0) *flag = (mf < mb) ? 1 : 0;
}

// ---------------------------------------------------------------------------
// RMSNorm over H=2048 per row -> bf16 out.
// ---------------------------------------------------------------------------
template <bool INRAW>
__global__ __launch_bounds__(256) void rmsnorm_k(const void* __restrict__ xin,
                                                 const void* __restrict__ w,
                                                 bf16* __restrict__ out,
                                                 const int* __restrict__ dtp) {
  const int f    = *dtp;
  const int row  = blockIdx.x;
  const int tid  = threadIdx.x;
  const int base = row * H_ + tid * 8;

  float v[8];
  if (INRAW && f) {
    const float* xf = (const float*)xin + base;
    f32x4 a = *(const f32x4*)xf, b = *(const f32x4*)(xf + 4);
#pragma unroll
    for (int i = 0; i < 4; ++i) { v[i] = a[i]; v[4 + i] = b[i]; }
  } else {
    bf16x8 t = *(const bf16x8*)((const bf16*)xin + base);
#pragma unroll
    for (int i = 0; i < 8; ++i) v[i] = (float)t[i];
  }

  float ss = 0.f;
#pragma unroll
  for (int i = 0; i < 8; ++i) ss += v[i] * v[i];
#pragma unroll
  for (int off = 1; off < 64; off <<= 1) ss += __shfl_xor(ss, off, 64);

  __shared__ float red[4];
  if ((tid & 63) == 0) red[tid >> 6] = ss;
  __syncthreads();
  ss = red[0] + red[1] + red[2] + red[3];

  const float scale = rsqrtf(ss * (1.0f / H_) + 1e-6f);
  float wv[8];
  if (f) {
    const float* wf = (const float*)w + tid * 8;
    f32x4 a = *(const f32x4*)wf, b = *(const f32x4*)(wf + 4);
#pragma unroll
    for (int i = 0; i < 4; ++i) { wv[i] = a[i]; wv[4 + i] = b[i]; }
  } else {
    bf16x8 t = *(const bf16x8*)((const bf16*)w + tid * 8);
#pragma unroll
    for (int i = 0; i < 8; ++i) wv[i] = (float)t[i];
  }
  bf16x8 o;
#pragma unroll
  for (int i = 0; i < 8; ++i) o[i] = (bf16)(wv[i] * (v[i] * scale));
  *(bf16x8*)(out + base) = o;
}

// ---------------------------------------------------------------------------
// Weight convert+transpose: W (raw [K,N], fp32 or bf16 per dtp) -> bf16 Wt [N,K].
// 64x64 tiles; coalesced in and out. Tiny (~350MB/iter total across 7 weights).
// ---------------------------------------------------------------------------
__global__ __launch_bounds__(256) void convert_wt(const void* __restrict__ W,
                                                  bf16* __restrict__ Wt,
                                                  const int K, const int N,
                                                  const int* __restrict__ dtp) {
  __shared__ bf16 sT[64][72];
  const int f   = *dtp;
  const int tid = threadIdx.x;
  const int k0  = blockIdx.y * 64;
  const int n0  = blockIdx.x * 64;
  if (f) {
#pragma unroll
    for (int p = 0; p < 4; ++p) {
      const int g  = tid + p * 256;
      const int r  = g >> 4;
      const int c4 = (g & 15) * 4;
      f32x4 v = *(const f32x4*)((const float*)W + (size_t)(k0 + r) * N + n0 + c4);
#pragma unroll
      for (int u = 0; u < 4; ++u) sT[c4 + u][r] = (bf16)v[u];
    }
  } else {
#pragma unroll
    for (int p = 0; p < 2; ++p) {
      const int g  = tid + p * 256;
      const int r  = g >> 3;
      const int c8 = (g & 7) * 8;
      bf16x8 v = *(const bf16x8*)((const bf16*)W + (size_t)(k0 + r) * N + n0 + c8);
#pragma unroll
      for (int u = 0; u < 8; ++u) sT[c8 + u][r] = v[u];
    }
  }
  __syncthreads();
#pragma unroll
  for (int p = 0; p < 2; ++p) {
    const int g  = tid + p * 256;
    const int n  = g >> 3;
    const int k8 = (g & 7) * 8;
    bf16x8 ov;
#pragma unroll
    for (int u = 0; u < 8; ++u) ov[u] = sT[n][k8 + u];
    *(bf16x8*)(Wt + (size_t)(n0 + n) * K + k0 + k8) = ov;
  }
}

// ---------------------------------------------------------------------------
// Fast GEMM (m97 structure): C[M,N] = A[M,K] @ Bt[N,K]^T, both bf16.
// 128x128 tile, BK=32, 4 waves, global_load_lds width-16 staging (linear LDS,
// zero staging bank conflicts), contiguous ds_read_b128 fragment loads.
// EPI: 0 plain; 1 acc+aux residual; 2 silu(aux)*acc.
// ---------------------------------------------------------------------------
template <int EPI, bool AUXRAW, bool CRAW>
__global__ __launch_bounds__(256) void gemm_bt_k(const bf16* __restrict__ A,
                                                 const bf16* __restrict__ Bt,
                                                 void* __restrict__ C,
                                                 const void* __restrict__ aux,
                                                 const int M, const int N, const int K,
                                                 const int* __restrict__ dtp) {
  __shared__ __align__(16) bf16 sA[128][32];
  __shared__ __align__(16) bf16 sB[128][32];

  const int f    = *dtp;
  const int tid  = threadIdx.x;
  const int lane = tid & 63;
  const int wave = tid >> 6;
  const int wm   = (wave >> 1) * 64;
  const int wn   = (wave & 1) * 64;
  const int row0 = blockIdx.y * 128;
  const int col0 = blockIdx.x * 128;
  const int l15  = lane & 15;
  const int quad = lane >> 4;

  f32x4 acc[4][4];
#pragma unroll
  for (int i = 0; i < 4; ++i)
#pragma unroll
    for (int j = 0; j < 4; ++j)
#pragma unroll
      for (int r = 0; r < 4; ++r) acc[i][j][r] = 0.f;

  // staging geometry: LDS byte o (tile is [128 rows][64B]) -> row o>>6, byte o&63
  const int o  = tid * 16;
  const int r0 = o >> 6;      // 0..63 (pass 0); pass 1 covers rows 64..127
  const int ib = o & 63;

  const char* gA0 = (const char*)(A  + (size_t)(row0 + r0)      * K) + ib;
  const char* gA1 = (const char*)(A  + (size_t)(row0 + 64 + r0) * K) + ib;
  const char* gB0 = (const char*)(Bt + (size_t)(col0 + r0)      * K) + ib;
  const char* gB1 = (const char*)(Bt + (size_t)(col0 + 64 + r0) * K) + ib;
  char* lA = (char*)(&sA[0][0]) + wave * 1024;   // wave-uniform
  char* lB = (char*)(&sB[0][0]) + wave * 1024;

  for (int k0 = 0; k0 < K; k0 += 32) {
    async16(gA0, lA);
    async16(gA1, lA + 4096);
    async16(gB0, lB);
    async16(gB1, lB + 4096);
    gA0 += 64; gA1 += 64; gB0 += 64; gB1 += 64;
    __syncthreads();   // drains vmcnt -> tiles visible

    bf16x8 af[4], bfr[4];
#pragma unroll
    for (int i = 0; i < 4; ++i)
      af[i] = *(const bf16x8*)(&sA[wm + i * 16 + l15][quad * 8]);
#pragma unroll
    for (int j = 0; j < 4; ++j)
      bfr[j] = *(const bf16x8*)(&sB[wn + j * 16 + l15][quad * 8]);
#pragma unroll
    for (int i = 0; i < 4; ++i)
#pragma unroll
      for (int j = 0; j < 4; ++j)
        acc[i][j] = __builtin_amdgcn_mfma_f32_16x16x32_bf16(af[i], bfr[j],
                                                            acc[i][j], 0, 0, 0);
    __syncthreads();   // all reads done before next overwrite
  }

#pragma unroll
  for (int i = 0; i < 4; ++i) {
#pragma unroll
    for (int j = 0; j < 4; ++j) {
#pragma unroll
      for (int r = 0; r < 4; ++r) {
        const int row    = row0 + wm + i * 16 + quad * 4 + r;
        const int col    = col0 + wn + j * 16 + l15;
        const size_t idx = (size_t)row * N + col;
        const float val  = acc[i][j][r];
        float outv;
        if (EPI == 0) {
          outv = val;
        } else {
          const float av = (AUXRAW && f) ? ((const float*)aux)[idx]
                                         : (float)((const bf16*)aux)[idx];
          if (EPI == 1) {
            outv = val + av;
          } else {
            const float sg = av / (1.f + __expf(-av));
            outv = sg * val;
          }
        }
        if (CRAW && f) ((float*)C)[idx] = outv;
        else           ((bf16*)C)[idx]  = (bf16)outv;
      }
    }
  }
}

// ---------------------------------------------------------------------------
// Legacy GEMM (fallback when workspace can't hold the B^T scratch).
// ---------------------------------------------------------------------------
template <int EPI, bool AUXRAW, bool CRAW>
__global__ __launch_bounds__(256) void gemm_k(const bf16* __restrict__ A,
                                              const void* __restrict__ Bm,
                                              void* __restrict__ C,
                                              const void* __restrict__ aux,
                                              const int M, const int N, const int K,
                                              const int* __restrict__ dtp) {
  __shared__ __align__(16) bf16 sA[128][40];
  __shared__ __align__(16) bf16 sB[128][40];

  const int f    = *dtp;
  const int tid  = threadIdx.x;
  const int lane = tid & 63;
  const int wave = tid >> 6;
  const int wm   = (wave >> 1) * 64;
  const int wn   = (wave & 1) * 64;
  const int row0 = blockIdx.y * 128;
  const int col0 = blockIdx.x * 128;
  const int l15  = lane & 15;
  const int quad = lane >> 4;

  f32x4 acc[4][4];
#pragma unroll
  for (int i = 0; i < 4; ++i)
#pragma unroll
    for (int j = 0; j < 4; ++j)
#pragma unroll
      for (int r = 0; r < 4; ++r) acc[i][j][r] = 0.f;

  for (int k0 = 0; k0 < K; k0 += 32) {
#pragma unroll
    for (int pass = 0; pass < 2; ++pass) {
      const int g  = tid + pass * 256;
      const int ar = g >> 2, ac = (g & 3) * 8;
      *(bf16x8*)(&sA[ar][ac]) =
          *(const bf16x8*)(A + (size_t)(row0 + ar) * K + k0 + ac);
      const int br = g >> 4, bc = (g & 15) * 8;
      const size_t boff = (size_t)(k0 + br) * N + col0 + bc;
      bf16x8 bv;
      if (f) {
        const float* bp = (const float*)Bm + boff;
        f32x4 lo = *(const f32x4*)bp, hi = *(const f32x4*)(bp + 4);
#pragma unroll
        for (int u = 0; u < 8; ++u) bv[u] = (bf16)(u < 4 ? lo[u] : hi[u - 4]);
      } else {
        bv = *(const bf16x8*)((const bf16*)Bm + boff);
      }
#pragma unroll
      for (int u = 0; u < 8; ++u) sB[bc + u][br] = bv[u];
    }
    __syncthreads();

    bf16x8 af[4], bfr[4];
#pragma unroll
    for (int i = 0; i < 4; ++i)
      af[i] = *(const bf16x8*)(&sA[wm + i * 16 + l15][quad * 8]);
#pragma unroll
    for (int j = 0; j < 4; ++j)
      bfr[j] = *(const bf16x8*)(&sB[wn + j * 16 + l15][quad * 8]);
#pragma unroll
    for (int i = 0; i < 4; ++i)
#pragma unroll
      for (int j = 0; j < 4; ++j)
        acc[i][j] = __builtin_amdgcn_mfma_f32_16x16x32_bf16(af[i], bfr[j],
                                                            acc[i][j], 0, 0, 0);
    __syncthreads();
  }

#pragma unroll
  for (int i = 0; i < 4; ++i) {
#pragma unroll
    for (int j = 0; j < 4; ++j) {
#pragma unroll
      for (int r = 0; r < 4; ++r) {
        const int row    = row0 + wm + i * 16 + quad * 4 + r;
        const int col    = col0 + wn + j * 16 + l15;
        const size_t idx = (size_t)row * N + col;
        const float val  = acc[i][j][r];
        float outv;
        if (EPI == 0) {
          outv = val;
        } else {
          const float av = (AUXRAW && f) ? ((const float*)aux)[idx]
                                         : (float)((const bf16*)aux)[idx];
          if (EPI == 1) {
            outv = val + av;
          } else {
            const float sg = av / (1.f + __expf(-av));
            outv = sg * val;
          }
        }
        if (CRAW && f) ((float*)C)[idx] = outv;
        else           ((bf16*)C)[idx]  = (bf16)outv;
      }
    }
  }
}

// ---------------------------------------------------------------------------
// RoPE + QK-RMSNorm, in place on q [M,2048] and k [M,512].
// ---------------------------------------------------------------------------
__global__ __launch_bounds__(256) void rope_norm_k(bf16* __restrict__ q,
                                                   bf16* __restrict__ k,
                                                   const void* __restrict__ qw,
                                                   const void* __restrict__ kw,
                                                   const int* __restrict__ dtp) {
  const int f    = *dtp;
  const int task = blockIdx.x * 4 + (threadIdx.x >> 6);
  const int lane = threadIdx.x & 63;
  const int row  = task / 20;
  const int hh   = task - row * 20;

  bf16* p;
  const void* w;
  if (hh < NH_) { p = q + (size_t)row * 2048 + hh * 128;        w = qw; }
  else          { p = k + (size_t)row * 512 + (hh - NH_) * 128; w = kw; }

  const float pos = (float)(row & (S_ - 1));
  const float inv = powf(10000.f, -(float)lane * (1.f / 64.f));
  float sn, cs;
  sincosf(pos * inv, &sn, &cs);

  const float x0 = (float)p[lane], x1 = (float)p[lane + 64];
  const float r0 = x0 * cs - x1 * sn;
  const float r1 = x1 * cs + x0 * sn;

  float ss = r0 * r0 + r1 * r1;
#pragma unroll
  for (int off = 1; off < 64; off <<= 1) ss += __shfl_xor(ss, off, 64);
  const float scale = rsqrtf(ss * (1.f / 128.f) + 1e-6f);

  const float w0 = f ? ((const float*)w)[lane]      : (float)((const bf16*)w)[lane];
  const float w1 = f ? ((const float*)w)[lane + 64] : (float)((const bf16*)w)[lane + 64];
  p[lane]      = (bf16)(w0 * (r0 * scale));
  p[lane + 64] = (bf16)(w1 * (r1 * scale));
}

// ---------------------------------------------------------------------------
// V transpose: v [M,512] -> vt [B][512][S] (key-contiguous for PV B-operand).
// ---------------------------------------------------------------------------
__global__ __launch_bounds__(256) void transpose_v(const bf16* __restrict__ v,
                                                   bf16* __restrict__ vt) {
  __shared__ bf16 sT[64][68];
  const int tid = threadIdx.x;
  const int r0  = blockIdx.y * 64;   // token-row block (never crosses b)
  const int c0  = blockIdx.x * 64;   // col block in [0,512)
  const int b   = r0 >> 11;
  const int s0  = r0 & 2047;
#pragma unroll
  for (int p = 0; p < 2; ++p) {
    const int g   = tid + p * 256;
    const int row = g >> 3;
    const int c8  = (g & 7) * 8;
    bf16x8 tv = *(const bf16x8*)(v + (size_t)(r0 + row) * 512 + c0 + c8);
#pragma unroll
    for (int u = 0; u < 8; ++u) sT[c8 + u][row] = tv[u];
  }
  __syncthreads();
#pragma unroll
  for (int p = 0; p < 2; ++p) {
    const int g  = tid + p * 256;
    const int oc = g >> 3;
    const int s8 = (g & 7) * 8;
    bf16x8 ov;
#pragma unroll
    for (int u = 0; u < 8; ++u) ov[u] = sT[oc][s8 + u];
    *(bf16x8*)(vt + ((size_t)(b * 512 + c0 + oc)) * 2048 + s0 + s8) = ov;
  }
}

// ---------------------------------------------------------------------------
// MFMA flash attention (causal, GQA). Unchanged from verified kernel.
// ---------------------------------------------------------------------------
__global__ __launch_bounds__(256) void attn_mfma(const bf16* __restrict__ q,
                                                 const bf16* __restrict__ k,
                                                 const bf16* __restrict__ vt,
                                                 bf16* __restrict__ ctx) {
  __shared__ __align__(16) bf16 sK[64][136];     // [key][dim]
  __shared__ __align__(16) bf16 sV[128][72];     // [dim][key]  (from vt)
  __shared__ __align__(16) bf16 sP[4][16][72];   // per-wave P tile

  const int tid  = threadIdx.x;
  const int lane = tid & 63;
  const int wave = tid >> 6;
  const int l15  = lane & 15;
  const int quad = lane >> 4;

  const int bid = blockIdx.x;
  const int i7  = bid & 127;
  const int qt  = (i7 & 1) ? (127 - (i7 >> 1)) : (i7 >> 1);  // work pairing
  const int kvh = (bid >> 7) & 3;
  const int b   = bid >> 9;
  const int q0  = qt * 16;
  const int h   = kvh * 4 + wave;

  bf16x8 qf[4];
  {
    const bf16* qp = q + (size_t)(b * S_ + q0 + l15) * 2048 + h * 128 + quad * 8;
#pragma unroll
    for (int c = 0; c < 4; ++c) qf[c] = *(const bf16x8*)(qp + c * 32);
  }

  float m4[4], l4[4];
  f32x4 of[8];
#pragma unroll
  for (int r = 0; r < 4; ++r) { m4[r] = -1e30f; l4[r] = 0.f; }
#pragma unroll
  for (int dg = 0; dg < 8; ++dg)
#pragma unroll
    for (int r = 0; r < 4; ++r) of[dg][r] = 0.f;

  const int ntiles = (q0 + 16 + 63) >> 6;
  const bf16* kbase = k + (size_t)b * S_ * 512 + kvh * 128;
  const bf16* vbase = vt + (size_t)(b * 512 + kvh * 128) * 2048;
  const float sc = 0.088388347648318447f;  // 1/sqrt(128)

  for (int t = 0; t < ntiles; ++t) {
    const int j0 = t << 6;
#pragma unroll
    for (int p = 0; p < 4; ++p) {
      const int g   = tid + p * 256;
      const int dc  = g & 15;
      const int key = g >> 4;
      *(bf16x8*)(&sK[key][dc * 8]) =
          *(const bf16x8*)(kbase + (size_t)(j0 + key) * 512 + dc * 8);
    }
#pragma unroll
    for (int p = 0; p < 4; ++p) {
      const int g   = tid + p * 256;
      const int dim = g >> 3;
      const int k8  = (g & 7) * 8;
      *(bf16x8*)(&sV[dim][k8]) =
          *(const bf16x8*)(vbase + (size_t)dim * 2048 + j0 + k8);
    }
    __syncthreads();

    f32x4 sa[4];
#pragma unroll
    for (int g = 0; g < 4; ++g)
#pragma unroll
      for (int r = 0; r < 4; ++r) sa[g][r] = 0.f;
#pragma unroll
    for (int g = 0; g < 4; ++g)
#pragma unroll
      for (int c = 0; c < 4; ++c) {
        bf16x8 kf = *(const bf16x8*)(&sK[g * 16 + l15][c * 32 + quad * 8]);
        sa[g] = __builtin_amdgcn_mfma_f32_16x16x32_bf16(qf[c], kf, sa[g], 0, 0, 0);
      }

    float s[4][4];
    const bool mask = (t == ntiles - 1);
#pragma unroll
    for (int g = 0; g < 4; ++g)
#pragma unroll
      for (int r = 0; r < 4; ++r) {
        float x = sa[g][r] * sc;
        if (mask && (j0 + g * 16 + l15 > q0 + quad * 4 + r)) x = -1e30f;
        s[g][r] = x;
      }

    float al[4];
#pragma unroll
    for (int r = 0; r < 4; ++r) {
      float rm = fmaxf(fmaxf(s[0][r], s[1][r]), fmaxf(s[2][r], s[3][r]));
#pragma unroll
      for (int off = 1; off < 16; off <<= 1) rm = fmaxf(rm, __shfl_xor(rm, off, 64));
      const float mn = fmaxf(m4[r], rm);
      al[r] = __expf(m4[r] - mn);
      float rs = 0.f;
#pragma unroll
      for (int g = 0; g < 4; ++g) { s[g][r] = __expf(s[g][r] - mn); rs += s[g][r]; }
#pragma unroll
      for (int off = 1; off < 16; off <<= 1) rs += __shfl_xor(rs, off, 64);
      l4[r] = l4[r] * al[r] + rs;
      m4[r] = mn;
    }
#pragma unroll
    for (int dg = 0; dg < 8; ++dg)
#pragma unroll
      for (int r = 0; r < 4; ++r) of[dg][r] *= al[r];

#pragma unroll
    for (int g = 0; g < 4; ++g)
#pragma unroll
      for (int r = 0; r < 4; ++r)
        sP[wave][quad * 4 + r][g * 16 + l15] = (bf16)s[g][r];
    bf16x8 pf[2];
#pragma unroll
    for (int c = 0; c < 2; ++c)
      pf[c] = *(const bf16x8*)(&sP[wave][l15][c * 32 + quad * 8]);

#pragma unroll
    for (int c = 0; c < 2; ++c)
#pragma unroll
      for (int dg = 0; dg < 8; ++dg) {
        bf16x8 vf = *(const bf16x8*)(&sV[dg * 16 + l15][c * 32 + quad * 8]);
        of[dg] = __builtin_amdgcn_mfma_f32_16x16x32_bf16(pf[c], vf, of[dg], 0, 0, 0);
      }
    __syncthreads();
  }

  bf16* op = ctx + (size_t)(b * S_ + q0) * 2048 + h * 128;
#pragma unroll
  for (int r = 0; r < 4; ++r) {
    const float rl = 1.f / l4[r];
    const int row  = quad * 4 + r;
#pragma unroll
    for (int dg = 0; dg < 8; ++dg)
      op[(size_t)row * 2048 + dg * 16 + l15] = (bf16)(of[dg][r] * rl);
  }
}

// ---------------------------------------------------------------------------
// Workspace (bf16 elements, after 16-byte flag slot):
//   slotA [8.4M elems] : h (rms1) -> ctx (attn out) -> h2 (rms2)
//   slotB [8.4M]       : q -> x1 residual
//   slotC [2.1M]       : k
//   slotD [2.1M]       : v (natural)
//   slotE [33.6M]      : vT (first 4MB, dead before MLP) -> g (Wg/silu*u)
//   wT    [16.8M]      : per-weight bf16 B^T scratch (fast path only)
// Fast path needs ~143 MB; falls back to legacy GEMM if ws smaller.
// ---------------------------------------------------------------------------
extern "C" void kernel_launch(void* const* d_in, const int* in_sizes, int n_in,
                              void* d_out, int out_size, void* d_ws, size_t ws_size,
                              hipStream_t stream) {
  (void)in_sizes; (void)n_in; (void)out_size;

  const void* hidden = d_in[0];
  const void* ln1 = d_in[3];
  const void* Wq  = d_in[4];
  const void* Wk  = d_in[5];
  const void* Wv  = d_in[6];
  const void* Wo  = d_in[7];
  const void* qn  = d_in[8];
  const void* kn  = d_in[9];
  const void* ln2 = d_in[10];
  const void* Wg  = d_in[11];
  const void* Wu  = d_in[12];
  const void* Wd  = d_in[13];

  int*  dtp   = (int*)d_ws;
  bf16* slotA = (bf16*)((char*)d_ws + 16);
  bf16* slotB = slotA + (size_t)M_ * 2048;
  bf16* slotC = slotB + (size_t)M_ * 2048;
  bf16* slotD = slotC + (size_t)M_ * 512;
  bf16* slotE = slotD + (size_t)M_ * 512;
  bf16* vT    = slotE;  // 2M elems at head of slotE; dead before Wg GEMM
  bf16* wT    = slotE + (size_t)M_ * 8192;  // weight B^T scratch (fast path)

  const size_t need = 16 + 2ull * ((size_t)M_ * 2048 * 2 + (size_t)M_ * 512 * 2 +
                                   (size_t)M_ * 8192 + (size_t)I_ * H_);

  probe_k<<<1, 64, 0, stream>>>((const uint32*)hidden, dtp);
  rmsnorm_k<true><<<M_, 256, 0, stream>>>(hidden, ln1, slotA, dtp);

  if (ws_size >= need) {
    // ---- fast path: JIT bf16 B^T weights + m97-structure GEMMs ----
    convert_wt<<<dim3(32, 32), 256, 0, stream>>>(Wq, wT, 2048, 2048, dtp);
    gemm_bt_k<0, false, false><<<dim3(16, 32), 256, 0, stream>>>(slotA, wT, slotB, nullptr, M_, 2048, 2048, dtp);
    convert_wt<<<dim3(8, 32), 256, 0, stream>>>(Wk, wT, 2048, 512, dtp);
    gemm_bt_k<0, false, false><<<dim3(4, 32), 256, 0, stream>>>(slotA, wT, slotC, nullptr, M_, 512, 2048, dtp);
    convert_wt<<<dim3(8, 32), 256, 0, stream>>>(Wv, wT, 2048, 512, dtp);
    gemm_bt_k<0, false, false><<<dim3(4, 32), 256, 0, stream>>>(slotA, wT, slotD, nullptr, M_, 512, 2048, dtp);
    transpose_v<<<dim3(8, 64), 256, 0, stream>>>(slotD, vT);
    rope_norm_k<<<(M_ * (NH_ + NKV_)) / 4, 256, 0, stream>>>(slotB, slotC, qn, kn, dtp);
    attn_mfma<<<B_ * NKV_ * (S_ / 16), 256, 0, stream>>>(slotB, slotC, vT, slotA);
    convert_wt<<<dim3(32, 32), 256, 0, stream>>>(Wo, wT, 2048, 2048, dtp);
    gemm_bt_k<1, true, false><<<dim3(16, 32), 256, 0, stream>>>(slotA, wT, slotB, hidden, M_, 2048, 2048, dtp);
    rmsnorm_k<false><<<M_, 256, 0, stream>>>(slotB, ln2, slotA, dtp);
    convert_wt<<<dim3(128, 32), 256, 0, stream>>>(Wg, wT, 2048, 8192, dtp);
    gemm_bt_k<0, false, false><<<dim3(64, 32), 256, 0, stream>>>(slotA, wT, slotE, nullptr, M_, 8192, 2048, dtp);
    convert_wt<<<dim3(128, 32), 256, 0, stream>>>(Wu, wT, 2048, 8192, dtp);
    gemm_bt_k<2, false, false><<<dim3(64, 32), 256, 0, stream>>>(slotA, wT, slotE, slotE, M_, 8192, 2048, dtp);
    convert_wt<<<dim3(32, 128), 256, 0, stream>>>(Wd, wT, 8192, 2048, dtp);
    gemm_bt_k<1, false, true><<<dim3(16, 32), 256, 0, stream>>>(slotE, wT, d_out, slotB, M_, 2048, 8192, dtp);
  } else {
    // ---- fallback: legacy in-GEMM conversion path (verified) ----
    gemm_k<0, false, false><<<dim3(16, 32), 256, 0, stream>>>(slotA, Wq, slotB, nullptr, M_, 2048, 2048, dtp);
    gemm_k<0, false, false><<<dim3(4, 32), 256, 0, stream>>>(slotA, Wk, slotC, nullptr, M_, 512, 2048, dtp);
    gemm_k<0, false, false><<<dim3(4, 32), 256, 0, stream>>>(slotA, Wv, slotD, nullptr, M_, 512, 2048, dtp);
    transpose_v<<<dim3(8, 64), 256, 0, stream>>>(slotD, vT);
    rope_norm_k<<<(M_ * (NH_ + NKV_)) / 4, 256, 0, stream>>>(slotB, slotC, qn, kn, dtp);
    attn_mfma<<<B_ * NKV_ * (S_ / 16), 256, 0, stream>>>(slotB, slotC, vT, slotA);
    gemm_k<1, true, false><<<dim3(16, 32), 256, 0, stream>>>(slotA, Wo, slotB, hidden, M_, 2048, 2048, dtp);
    rmsnorm_k<false><<<M_, 256, 0, stream>>>(slotB, ln2, slotA, dtp);
    gemm_k<0, false, false><<<dim3(64, 32), 256, 0, stream>>>(slotA, Wg, slotE, nullptr, M_, 8192, 2048, dtp);
    gemm_k<2, false, false><<<dim3(64, 32), 256, 0, stream>>>(slotA, Wu, slotE, slotE, M_, 8192, 2048, dtp);
    gemm_k<1, false, true><<<dim3(16, 32), 256, 0, stream>>>(slotE, Wd, d_out, slotB, M_, 2048, 8192, dtp);
  }
}

// Round 2
// 1419.571 us; speedup vs baseline: 2.0110x; 1.0750x over previous
//
#include <hip/hip_runtime.h>
#include <math.h>

typedef __bf16 bf16;
typedef bf16 bf16x8 __attribute__((ext_vector_type(8)));
typedef float f32x4 __attribute__((ext_vector_type(4)));
typedef unsigned int uint32;

#define B_   2
#define S_   2048
#define H_   2048
#define NH_  16
#define NKV_ 4
#define HD_  128
#define I_   8192
#define M_   (B_ * S_)   // 4096 token rows

// ---------------------------------------------------------------------------
// async global->LDS, 16B per lane. Dest is wave-uniform base + lane*16.
// ---------------------------------------------------------------------------
typedef __attribute__((address_space(3))) void       lds_void;
typedef __attribute__((address_space(1))) const void gbl_void;

__device__ __forceinline__ void async16(const void* g, void* l) {
  __builtin_amdgcn_global_load_lds((gbl_void*)g, (lds_void*)l, 16, 0, 0);
}

// ---------------------------------------------------------------------------
// Dtype probe: raw inputs fp32 vs bf16 (verified: fp32 on this harness).
// ---------------------------------------------------------------------------
__global__ void probe_k(const uint32* __restrict__ x, int* __restrict__ flag) {
  const int lane = threadIdx.x;
  const uint32 u = x[lane];
  float blo = fabsf(__uint_as_float(u << 16));
  float bhi = fabsf(__uint_as_float(u & 0xffff0000u));
  float fv  = fabsf(__uint_as_float(u));
  if (!(blo < 1e30f)) blo = 3e38f;
  if (!(bhi < 1e30f)) bhi = 3e38f;
  if (!(fv  < 1e30f)) fv  = 3e38f;
  float mb = fmaxf(blo, bhi);
  float mf = fv;
#pragma unroll
  for (int off = 1; off < 64; off <<= 1) {
    mb = fmaxf(mb, __shfl_xor(mb, off, 64));
    mf = fmaxf(mf, __shfl_xor(mf, off, 64));
  }
  if (lane == 0) *flag = (mf < mb) ? 1 : 0;
}

// ---------------------------------------------------------------------------
// RMSNorm over H=2048 per row -> bf16 out.
// ---------------------------------------------------------------------------
template <bool INRAW>
__global__ __launch_bounds__(256) void rmsnorm_k(const void* __restrict__ xin,
                                                 const void* __restrict__ w,
                                                 bf16* __restrict__ out,
                                                 const int* __restrict__ dtp) {
  const int f    = *dtp;
  const int row  = blockIdx.x;
  const int tid  = threadIdx.x;
  const int base = row * H_ + tid * 8;

  float v[8];
  if (INRAW && f) {
    const float* xf = (const float*)xin + base;
    f32x4 a = *(const f32x4*)xf, b = *(const f32x4*)(xf + 4);
#pragma unroll
    for (int i = 0; i < 4; ++i) { v[i] = a[i]; v[4 + i] = b[i]; }
  } else {
    bf16x8 t = *(const bf16x8*)((const bf16*)xin + base);
#pragma unroll
    for (int i = 0; i < 8; ++i) v[i] = (float)t[i];
  }

  float ss = 0.f;
#pragma unroll
  for (int i = 0; i < 8; ++i) ss += v[i] * v[i];
#pragma unroll
  for (int off = 1; off < 64; off <<= 1) ss += __shfl_xor(ss, off, 64);

  __shared__ float red[4];
  if ((tid & 63) == 0) red[tid >> 6] = ss;
  __syncthreads();
  ss = red[0] + red[1] + red[2] + red[3];

  const float scale = rsqrtf(ss * (1.0f / H_) + 1e-6f);
  float wv[8];
  if (f) {
    const float* wf = (const float*)w + tid * 8;
    f32x4 a = *(const f32x4*)wf, b = *(const f32x4*)(wf + 4);
#pragma unroll
    for (int i = 0; i < 4; ++i) { wv[i] = a[i]; wv[4 + i] = b[i]; }
  } else {
    bf16x8 t = *(const bf16x8*)((const bf16*)w + tid * 8);
#pragma unroll
    for (int i = 0; i < 8; ++i) wv[i] = (float)t[i];
  }
  bf16x8 o;
#pragma unroll
  for (int i = 0; i < 8; ++i) o[i] = (bf16)(wv[i] * (v[i] * scale));
  *(bf16x8*)(out + base) = o;
}

// ---------------------------------------------------------------------------
// Weight convert+transpose: W (raw [K,N], fp32 or bf16 per dtp) -> bf16 Wt [N,K].
// ---------------------------------------------------------------------------
__global__ __launch_bounds__(256) void convert_wt(const void* __restrict__ W,
                                                  bf16* __restrict__ Wt,
                                                  const int K, const int N,
                                                  const int* __restrict__ dtp) {
  __shared__ bf16 sT[64][72];
  const int f   = *dtp;
  const int tid = threadIdx.x;
  const int k0  = blockIdx.y * 64;
  const int n0  = blockIdx.x * 64;
  if (f) {
#pragma unroll
    for (int p = 0; p < 4; ++p) {
      const int g  = tid + p * 256;
      const int r  = g >> 4;
      const int c4 = (g & 15) * 4;
      f32x4 v = *(const f32x4*)((const float*)W + (size_t)(k0 + r) * N + n0 + c4);
#pragma unroll
      for (int u = 0; u < 4; ++u) sT[c4 + u][r] = (bf16)v[u];
    }
  } else {
#pragma unroll
    for (int p = 0; p < 2; ++p) {
      const int g  = tid + p * 256;
      const int r  = g >> 3;
      const int c8 = (g & 7) * 8;
      bf16x8 v = *(const bf16x8*)((const bf16*)W + (size_t)(k0 + r) * N + n0 + c8);
#pragma unroll
      for (int u = 0; u < 8; ++u) sT[c8 + u][r] = v[u];
    }
  }
  __syncthreads();
#pragma unroll
  for (int p = 0; p < 2; ++p) {
    const int g  = tid + p * 256;
    const int n  = g >> 3;
    const int k8 = (g & 7) * 8;
    bf16x8 ov;
#pragma unroll
    for (int u = 0; u < 8; ++u) ov[u] = sT[n][k8 + u];
    *(bf16x8*)(Wt + (size_t)(n0 + n) * K + k0 + k8) = ov;
  }
}

// ---------------------------------------------------------------------------
// 256x256 8-phase GEMM (m201 template, plain HIP): C[M,N] = A[M,K] @ Bt[N,K]^T.
// BK=64, 8 waves (2M x 4N), 128 KiB LDS double-buffer, global_load_lds staging
// with pre-swizzled source + XOR-swizzled ds_read (byte ^= (row&7)<<4),
// counted vmcnt(6) at phases 4/8 only, setprio(1) around MFMA clusters.
// Wave m-rows interleaved across both 128-halves so each contiguous 16KB
// half-tile dies early (WAR-safe prefetch into the live buffer).
// Requires M%256==0, N%256==0, K%128==0.
// ---------------------------------------------------------------------------
#define BARX() do { asm volatile("" ::: "memory");                       \
                    __builtin_amdgcn_s_barrier();                        \
                    asm volatile("" ::: "memory"); } while (0)
#define VMW6() asm volatile("s_waitcnt vmcnt(6)" ::: "memory")

template <int EPI, bool AUXRAW, bool CRAW>
__global__ __launch_bounds__(512, 2) void gemm8_k(const bf16* __restrict__ A,
                                                  const bf16* __restrict__ Bt,
                                                  void* __restrict__ C,
                                                  const void* __restrict__ aux,
                                                  const int M, const int N,
                                                  const int K,
                                                  const int* __restrict__ dtp) {
  __shared__ __align__(16) bf16 sA[2][256][64];   // 64 KiB
  __shared__ __align__(16) bf16 sB[2][256][64];   // 64 KiB

  const int f    = *dtp;
  const int tid  = threadIdx.x;
  const int lane = tid & 63;
  const int wave = tid >> 6;
  const int wr   = wave >> 2;    // 0..1  (row half of wave grid)
  const int wc   = wave & 3;     // 0..3  (col quarter)
  const int l15  = lane & 15;
  const int quad = lane >> 4;

  // XCD-aware bijective swizzle (all grids used are multiples of 8)
  const int gx  = gridDim.x;
  const int nwg = gx * gridDim.y;
  int bid = blockIdx.y * gx + blockIdx.x;
  if ((nwg & 7) == 0) bid = (bid & 7) * (nwg >> 3) + (bid >> 3);
  const int row0 = (bid / gx) * 256;
  const int col0 = (bid % gx) * 256;

  const int NT = K >> 6;   // K-tiles of 64 (even for all shapes used)

  // ---- fragment-read addressing (swizzled): row&7 == l15&7 everywhere ----
  const int swo = (l15 & 7) << 4;
  const int cb0 = (quad * 16) ^ swo;        // kk=0 column bytes
  const int cb1 = (64 + quad * 16) ^ swo;   // kk=1
  char* sAc = (char*)&sA[0][0][0];
  char* sBc = (char*)&sB[0][0][0];

  // ---- staging source (inverse-swizzled global address, linear LDS dest) ----
  const int d0   = tid * 16;
  const int d1   = 8192 + tid * 16;
  const int p0   = d0 ^ (((d0 >> 7) & 7) << 4);
  const int p1   = d1 ^ (((d1 >> 7) & 7) << 4);
  const int rg0  = p0 >> 7, cbs0 = p0 & 127;
  const int rg1  = p1 >> 7, cbs1 = p1 & 127;
  const size_t K2 = (size_t)K * 2;
  const char* gA = (const char*)A  + (size_t)row0 * K2;
  const char* gB = (const char*)Bt + (size_t)col0 * K2;

#define STAGE8(gbase, sbase, s, h, t) do {                                     \
    const int tt_ = ((t) < NT) ? (t) : ((t) - NT);                             \
    const size_t go_ = (size_t)tt_ * 128;                                      \
    async16(gbase + (size_t)((h) * 128 + rg0) * K2 + go_ + cbs0,               \
            (sbase) + (s) * 32768 + (h) * 16384 + tid * 16);                   \
    async16(gbase + (size_t)((h) * 128 + rg1) * K2 + go_ + cbs1,               \
            (sbase) + (s) * 32768 + (h) * 16384 + 8192 + tid * 16);            \
  } while (0)
#define STA(s, h, t) STAGE8(gA, sAc, s, h, t)
#define STB(s, h, t) STAGE8(gB, sBc, s, h, t)

  bf16x8 af[4][2], bfr[2][2];
  f32x4 acc[8][4];
#pragma unroll
  for (int m = 0; m < 8; ++m)
#pragma unroll
    for (int n = 0; n < 4; ++n)
#pragma unroll
      for (int r = 0; r < 4; ++r) acc[m][n][r] = 0.f;

#define LDA8(s, mh) do {                                                       \
    _Pragma("unroll")                                                          \
    for (int mi = 0; mi < 4; ++mi) {                                           \
      const int rb = ((mh) * 128 + wr * 64 + mi * 16 + l15) * 128;             \
      af[mi][0] = *(const bf16x8*)(sAc + (s) * 32768 + rb + cb0);              \
      af[mi][1] = *(const bf16x8*)(sAc + (s) * 32768 + rb + cb1);              \
    }                                                                          \
  } while (0)

#define LDB8(s, nh) do {                                                       \
    _Pragma("unroll")                                                          \
    for (int ni = 0; ni < 2; ++ni) {                                           \
      const int rb = ((nh) * 128 + wc * 32 + ni * 16 + l15) * 128;             \
      bfr[ni][0] = *(const bf16x8*)(sBc + (s) * 32768 + rb + cb0);             \
      bfr[ni][1] = *(const bf16x8*)(sBc + (s) * 32768 + rb + cb1);             \
    }                                                                          \
  } while (0)

#define MFMA16(mh, nh) do {                                                    \
    __builtin_amdgcn_s_setprio(1);                                             \
    _Pragma("unroll")                                                          \
    for (int mi = 0; mi < 4; ++mi)                                             \
      _Pragma("unroll")                                                        \
      for (int ni = 0; ni < 2; ++ni) {                                         \
        acc[(mh)*4+mi][(nh)*2+ni] = __builtin_amdgcn_mfma_f32_16x16x32_bf16(   \
            af[mi][0], bfr[ni][0], acc[(mh)*4+mi][(nh)*2+ni], 0, 0, 0);        \
        acc[(mh)*4+mi][(nh)*2+ni] = __builtin_amdgcn_mfma_f32_16x16x32_bf16(   \
            af[mi][1], bfr[ni][1], acc[(mh)*4+mi][(nh)*2+ni], 0, 0, 0);        \
      }                                                                        \
    __builtin_amdgcn_s_setprio(0);                                             \
  } while (0)

  // ---- prologue: tile0 full + 3 halves of tile1; tile0 guaranteed landed ----
  STA(0, 0, 0); STA(0, 1, 0); STB(0, 0, 0); STB(0, 1, 0);
  STA(1, 0, 1); STA(1, 1, 1); STB(1, 0, 1);
  VMW6();
  BARX();

#pragma unroll 1
  for (int T = 0; T < NT; T += 2) {
    // ph1: tile T quad(0,0); stage hB1(T+1)->buf1 (dead since prev ph8)
    LDA8(0, 0); LDB8(0, 0);
    STB(1, 1, T + 1);
    BARX(); MFMA16(0, 0); BARX();
    // ph2: quad(0,1); stage hA0(T+2)->buf0 (A m0-3 dead after ph1)
    LDB8(0, 1);
    STA(0, 0, T + 2);
    BARX(); MFMA16(0, 1); BARX();
    // ph3: quad(1,0)
    LDA8(0, 1); LDB8(0, 0);
    BARX(); MFMA16(1, 0); BARX();
    // ph4: quad(1,1); stage hA1,hB0(T+2); vmcnt(6) -> tile T+1 landed
    LDB8(0, 1);
    STA(0, 1, T + 2); STB(0, 0, T + 2);
    BARX(); MFMA16(1, 1); VMW6(); BARX();
    // ph5: tile T+1 quad(0,0); stage hB1(T+2)->buf0 (dead after ph4)
    LDA8(1, 0); LDB8(1, 0);
    STB(0, 1, T + 2);
    BARX(); MFMA16(0, 0); BARX();
    // ph6: quad(0,1); stage hA0(T+3)->buf1 (dead after ph5)
    LDB8(1, 1);
    STA(1, 0, T + 3);
    BARX(); MFMA16(0, 1); BARX();
    // ph7: quad(1,0)
    LDA8(1, 1); LDB8(1, 0);
    BARX(); MFMA16(1, 0); BARX();
    // ph8: quad(1,1); stage hA1,hB0(T+3); vmcnt(6) -> tile T+2 landed
    LDB8(1, 1);
    STA(1, 1, T + 3); STB(1, 0, T + 3);
    BARX(); MFMA16(1, 1); VMW6(); BARX();
  }
  asm volatile("s_waitcnt vmcnt(0)" ::: "memory");

  // ---- epilogue (interleaved wave row/col mapping) ----
#pragma unroll
  for (int m = 0; m < 8; ++m) {
#pragma unroll
    for (int n = 0; n < 4; ++n) {
#pragma unroll
      for (int r = 0; r < 4; ++r) {
        const int row = row0 + (m >> 2) * 128 + wr * 64 + (m & 3) * 16 + quad * 4 + r;
        const int col = col0 + (n >> 1) * 128 + wc * 32 + (n & 1) * 16 + l15;
        const size_t idx = (size_t)row * N + col;
        const float val  = acc[m][n][r];
        float outv;
        if (EPI == 0) {
          outv = val;
        } else {
          const float av = (AUXRAW && f) ? ((const float*)aux)[idx]
                                         : (float)((const bf16*)aux)[idx];
          if (EPI == 1) {
            outv = val + av;
          } else {
            const float sg = av / (1.f + __expf(-av));
            outv = sg * val;
          }
        }
        if (CRAW && f) ((float*)C)[idx] = outv;
        else           ((bf16*)C)[idx]  = (bf16)outv;
      }
    }
  }
#undef STAGE8
#undef STA
#undef STB
#undef LDA8
#undef LDB8
#undef MFMA16
}

// ---------------------------------------------------------------------------
// 2-phase 128x128 GEMM (verified m97 structure): used for N=512 (Wk/Wv).
// ---------------------------------------------------------------------------
template <int EPI, bool AUXRAW, bool CRAW>
__global__ __launch_bounds__(256) void gemm_bt_k(const bf16* __restrict__ A,
                                                 const bf16* __restrict__ Bt,
                                                 void* __restrict__ C,
                                                 const void* __restrict__ aux,
                                                 const int M, const int N, const int K,
                                                 const int* __restrict__ dtp) {
  __shared__ __align__(16) bf16 sA[128][32];
  __shared__ __align__(16) bf16 sB[128][32];

  const int f    = *dtp;
  const int tid  = threadIdx.x;
  const int lane = tid & 63;
  const int wave = tid >> 6;
  const int wm   = (wave >> 1) * 64;
  const int wn   = (wave & 1) * 64;
  const int row0 = blockIdx.y * 128;
  const int col0 = blockIdx.x * 128;
  const int l15  = lane & 15;
  const int quad = lane >> 4;

  f32x4 acc[4][4];
#pragma unroll
  for (int i = 0; i < 4; ++i)
#pragma unroll
    for (int j = 0; j < 4; ++j)
#pragma unroll
      for (int r = 0; r < 4; ++r) acc[i][j][r] = 0.f;

  const int o  = tid * 16;
  const int r0 = o >> 6;
  const int ib = o & 63;

  const char* gA0 = (const char*)(A  + (size_t)(row0 + r0)      * K) + ib;
  const char* gA1 = (const char*)(A  + (size_t)(row0 + 64 + r0) * K) + ib;
  const char* gB0 = (const char*)(Bt + (size_t)(col0 + r0)      * K) + ib;
  const char* gB1 = (const char*)(Bt + (size_t)(col0 + 64 + r0) * K) + ib;
  char* lA = (char*)(&sA[0][0]) + wave * 1024;
  char* lB = (char*)(&sB[0][0]) + wave * 1024;

  for (int k0 = 0; k0 < K; k0 += 32) {
    async16(gA0, lA);
    async16(gA1, lA + 4096);
    async16(gB0, lB);
    async16(gB1, lB + 4096);
    gA0 += 64; gA1 += 64; gB0 += 64; gB1 += 64;
    __syncthreads();

    bf16x8 af[4], bfr[4];
#pragma unroll
    for (int i = 0; i < 4; ++i)
      af[i] = *(const bf16x8*)(&sA[wm + i * 16 + l15][quad * 8]);
#pragma unroll
    for (int j = 0; j < 4; ++j)
      bfr[j] = *(const bf16x8*)(&sB[wn + j * 16 + l15][quad * 8]);
#pragma unroll
    for (int i = 0; i < 4; ++i)
#pragma unroll
      for (int j = 0; j < 4; ++j)
        acc[i][j] = __builtin_amdgcn_mfma_f32_16x16x32_bf16(af[i], bfr[j],
                                                            acc[i][j], 0, 0, 0);
    __syncthreads();
  }

#pragma unroll
  for (int i = 0; i < 4; ++i) {
#pragma unroll
    for (int j = 0; j < 4; ++j) {
#pragma unroll
      for (int r = 0; r < 4; ++r) {
        const int row    = row0 + wm + i * 16 + quad * 4 + r;
        const int col    = col0 + wn + j * 16 + l15;
        const size_t idx = (size_t)row * N + col;
        const float val  = acc[i][j][r];
        float outv;
        if (EPI == 0) {
          outv = val;
        } else {
          const float av = (AUXRAW && f) ? ((const float*)aux)[idx]
                                         : (float)((const bf16*)aux)[idx];
          if (EPI == 1) {
            outv = val + av;
          } else {
            const float sg = av / (1.f + __expf(-av));
            outv = sg * val;
          }
        }
        if (CRAW && f) ((float*)C)[idx] = outv;
        else           ((bf16*)C)[idx]  = (bf16)outv;
      }
    }
  }
}

// ---------------------------------------------------------------------------
// Legacy GEMM (fallback when workspace can't hold the B^T scratch).
// ---------------------------------------------------------------------------
template <int EPI, bool AUXRAW, bool CRAW>
__global__ __launch_bounds__(256) void gemm_k(const bf16* __restrict__ A,
                                              const void* __restrict__ Bm,
                                              void* __restrict__ C,
                                              const void* __restrict__ aux,
                                              const int M, const int N, const int K,
                                              const int* __restrict__ dtp) {
  __shared__ __align__(16) bf16 sA[128][40];
  __shared__ __align__(16) bf16 sB[128][40];

  const int f    = *dtp;
  const int tid  = threadIdx.x;
  const int lane = tid & 63;
  const int wave = tid >> 6;
  const int wm   = (wave >> 1) * 64;
  const int wn   = (wave & 1) * 64;
  const int row0 = blockIdx.y * 128;
  const int col0 = blockIdx.x * 128;
  const int l15  = lane & 15;
  const int quad = lane >> 4;

  f32x4 acc[4][4];
#pragma unroll
  for (int i = 0; i < 4; ++i)
#pragma unroll
    for (int j = 0; j < 4; ++j)
#pragma unroll
      for (int r = 0; r < 4; ++r) acc[i][j][r] = 0.f;

  for (int k0 = 0; k0 < K; k0 += 32) {
#pragma unroll
    for (int pass = 0; pass < 2; ++pass) {
      const int g  = tid + pass * 256;
      const int ar = g >> 2, ac = (g & 3) * 8;
      *(bf16x8*)(&sA[ar][ac]) =
          *(const bf16x8*)(A + (size_t)(row0 + ar) * K + k0 + ac);
      const int br = g >> 4, bc = (g & 15) * 8;
      const size_t boff = (size_t)(k0 + br) * N + col0 + bc;
      bf16x8 bv;
      if (f) {
        const float* bp = (const float*)Bm + boff;
        f32x4 lo = *(const f32x4*)bp, hi = *(const f32x4*)(bp + 4);
#pragma unroll
        for (int u = 0; u < 8; ++u) bv[u] = (bf16)(u < 4 ? lo[u] : hi[u - 4]);
      } else {
        bv = *(const bf16x8*)((const bf16*)Bm + boff);
      }
#pragma unroll
      for (int u = 0; u < 8; ++u) sB[bc + u][br] = bv[u];
    }
    __syncthreads();

    bf16x8 af[4], bfr[4];
#pragma unroll
    for (int i = 0; i < 4; ++i)
      af[i] = *(const bf16x8*)(&sA[wm + i * 16 + l15][quad * 8]);
#pragma unroll
    for (int j = 0; j < 4; ++j)
      bfr[j] = *(const bf16x8*)(&sB[wn + j * 16 + l15][quad * 8]);
#pragma unroll
    for (int i = 0; i < 4; ++i)
#pragma unroll
      for (int j = 0; j < 4; ++j)
        acc[i][j] = __builtin_amdgcn_mfma_f32_16x16x32_bf16(af[i], bfr[j],
                                                            acc[i][j], 0, 0, 0);
    __syncthreads();
  }

#pragma unroll
  for (int i = 0; i < 4; ++i) {
#pragma unroll
    for (int j = 0; j < 4; ++j) {
#pragma unroll
      for (int r = 0; r < 4; ++r) {
        const int row    = row0 + wm + i * 16 + quad * 4 + r;
        const int col    = col0 + wn + j * 16 + l15;
        const size_t idx = (size_t)row * N + col;
        const float val  = acc[i][j][r];
        float outv;
        if (EPI == 0) {
          outv = val;
        } else {
          const float av = (AUXRAW && f) ? ((const float*)aux)[idx]
                                         : (float)((const bf16*)aux)[idx];
          if (EPI == 1) {
            outv = val + av;
          } else {
            const float sg = av / (1.f + __expf(-av));
            outv = sg * val;
          }
        }
        if (CRAW && f) ((float*)C)[idx] = outv;
        else           ((bf16*)C)[idx]  = (bf16)outv;
      }
    }
  }
}

// ---------------------------------------------------------------------------
// RoPE + QK-RMSNorm, in place on q [M,2048] and k [M,512].
// ---------------------------------------------------------------------------
__global__ __launch_bounds__(256) void rope_norm_k(bf16* __restrict__ q,
                                                   bf16* __restrict__ k,
                                                   const void* __restrict__ qw,
                                                   const void* __restrict__ kw,
                                                   const int* __restrict__ dtp) {
  const int f    = *dtp;
  const int task = blockIdx.x * 4 + (threadIdx.x >> 6);
  const int lane = threadIdx.x & 63;
  const int row  = task / 20;
  const int hh   = task - row * 20;

  bf16* p;
  const void* w;
  if (hh < NH_) { p = q + (size_t)row * 2048 + hh * 128;        w = qw; }
  else          { p = k + (size_t)row * 512 + (hh - NH_) * 128; w = kw; }

  const float pos = (float)(row & (S_ - 1));
  const float inv = powf(10000.f, -(float)lane * (1.f / 64.f));
  float sn, cs;
  sincosf(pos * inv, &sn, &cs);

  const float x0 = (float)p[lane], x1 = (float)p[lane + 64];
  const float r0 = x0 * cs - x1 * sn;
  const float r1 = x1 * cs + x0 * sn;

  float ss = r0 * r0 + r1 * r1;
#pragma unroll
  for (int off = 1; off < 64; off <<= 1) ss += __shfl_xor(ss, off, 64);
  const float scale = rsqrtf(ss * (1.f / 128.f) + 1e-6f);

  const float w0 = f ? ((const float*)w)[lane]      : (float)((const bf16*)w)[lane];
  const float w1 = f ? ((const float*)w)[lane + 64] : (float)((const bf16*)w)[lane + 64];
  p[lane]      = (bf16)(w0 * (r0 * scale));
  p[lane + 64] = (bf16)(w1 * (r1 * scale));
}

// ---------------------------------------------------------------------------
// V transpose: v [M,512] -> vt [B][512][S] (key-contiguous for PV B-operand).
// ---------------------------------------------------------------------------
__global__ __launch_bounds__(256) void transpose_v(const bf16* __restrict__ v,
                                                   bf16* __restrict__ vt) {
  __shared__ bf16 sT[64][68];
  const int tid = threadIdx.x;
  const int r0  = blockIdx.y * 64;
  const int c0  = blockIdx.x * 64;
  const int b   = r0 >> 11;
  const int s0  = r0 & 2047;
#pragma unroll
  for (int p = 0; p < 2; ++p) {
    const int g   = tid + p * 256;
    const int row = g >> 3;
    const int c8  = (g & 7) * 8;
    bf16x8 tv = *(const bf16x8*)(v + (size_t)(r0 + row) * 512 + c0 + c8);
#pragma unroll
    for (int u = 0; u < 8; ++u) sT[c8 + u][row] = tv[u];
  }
  __syncthreads();
#pragma unroll
  for (int p = 0; p < 2; ++p) {
    const int g  = tid + p * 256;
    const int oc = g >> 3;
    const int s8 = (g & 7) * 8;
    bf16x8 ov;
#pragma unroll
    for (int u = 0; u < 8; ++u) ov[u] = sT[oc][s8 + u];
    *(bf16x8*)(vt + ((size_t)(b * 512 + c0 + oc)) * 2048 + s0 + s8) = ov;
  }
}

// ---------------------------------------------------------------------------
// MFMA flash attention (causal, GQA). Unchanged from verified kernel.
// ---------------------------------------------------------------------------
__global__ __launch_bounds__(256) void attn_mfma(const bf16* __restrict__ q,
                                                 const bf16* __restrict__ k,
                                                 const bf16* __restrict__ vt,
                                                 bf16* __restrict__ ctx) {
  __shared__ __align__(16) bf16 sK[64][136];
  __shared__ __align__(16) bf16 sV[128][72];
  __shared__ __align__(16) bf16 sP[4][16][72];

  const int tid  = threadIdx.x;
  const int lane = tid & 63;
  const int wave = tid >> 6;
  const int l15  = lane & 15;
  const int quad = lane >> 4;

  const int bid = blockIdx.x;
  const int i7  = bid & 127;
  const int qt  = (i7 & 1) ? (127 - (i7 >> 1)) : (i7 >> 1);
  const int kvh = (bid >> 7) & 3;
  const int b   = bid >> 9;
  const int q0  = qt * 16;
  const int h   = kvh * 4 + wave;

  bf16x8 qf[4];
  {
    const bf16* qp = q + (size_t)(b * S_ + q0 + l15) * 2048 + h * 128 + quad * 8;
#pragma unroll
    for (int c = 0; c < 4; ++c) qf[c] = *(const bf16x8*)(qp + c * 32);
  }

  float m4[4], l4[4];
  f32x4 of[8];
#pragma unroll
  for (int r = 0; r < 4; ++r) { m4[r] = -1e30f; l4[r] = 0.f; }
#pragma unroll
  for (int dg = 0; dg < 8; ++dg)
#pragma unroll
    for (int r = 0; r < 4; ++r) of[dg][r] = 0.f;

  const int ntiles = (q0 + 16 + 63) >> 6;
  const bf16* kbase = k + (size_t)b * S_ * 512 + kvh * 128;
  const bf16* vbase = vt + (size_t)(b * 512 + kvh * 128) * 2048;
  const float sc = 0.088388347648318447f;

  for (int t = 0; t < ntiles; ++t) {
    const int j0 = t << 6;
#pragma unroll
    for (int p = 0; p < 4; ++p) {
      const int g   = tid + p * 256;
      const int dc  = g & 15;
      const int key = g >> 4;
      *(bf16x8*)(&sK[key][dc * 8]) =
          *(const bf16x8*)(kbase + (size_t)(j0 + key) * 512 + dc * 8);
    }
#pragma unroll
    for (int p = 0; p < 4; ++p) {
      const int g   = tid + p * 256;
      const int dim = g >> 3;
      const int k8  = (g & 7) * 8;
      *(bf16x8*)(&sV[dim][k8]) =
          *(const bf16x8*)(vbase + (size_t)dim * 2048 + j0 + k8);
    }
    __syncthreads();

    f32x4 sa[4];
#pragma unroll
    for (int g = 0; g < 4; ++g)
#pragma unroll
      for (int r = 0; r < 4; ++r) sa[g][r] = 0.f;
#pragma unroll
    for (int g = 0; g < 4; ++g)
#pragma unroll
      for (int c = 0; c < 4; ++c) {
        bf16x8 kf = *(const bf16x8*)(&sK[g * 16 + l15][c * 32 + quad * 8]);
        sa[g] = __builtin_amdgcn_mfma_f32_16x16x32_bf16(qf[c], kf, sa[g], 0, 0, 0);
      }

    float s[4][4];
    const bool mask = (t == ntiles - 1);
#pragma unroll
    for (int g = 0; g < 4; ++g)
#pragma unroll
      for (int r = 0; r < 4; ++r) {
        float x = sa[g][r] * sc;
        if (mask && (j0 + g * 16 + l15 > q0 + quad * 4 + r)) x = -1e30f;
        s[g][r] = x;
      }

    float al[4];
#pragma unroll
    for (int r = 0; r < 4; ++r) {
      float rm = fmaxf(fmaxf(s[0][r], s[1][r]), fmaxf(s[2][r], s[3][r]));
#pragma unroll
      for (int off = 1; off < 16; off <<= 1) rm = fmaxf(rm, __shfl_xor(rm, off, 64));
      const float mn = fmaxf(m4[r], rm);
      al[r] = __expf(m4[r] - mn);
      float rs = 0.f;
#pragma unroll
      for (int g = 0; g < 4; ++g) { s[g][r] = __expf(s[g][r] - mn); rs += s[g][r]; }
#pragma unroll
      for (int off = 1; off < 16; off <<= 1) rs += __shfl_xor(rs, off, 64);
      l4[r] = l4[r] * al[r] + rs;
      m4[r] = mn;
    }
#pragma unroll
    for (int dg = 0; dg < 8; ++dg)
#pragma unroll
      for (int r = 0; r < 4; ++r) of[dg][r] *= al[r];

#pragma unroll
    for (int g = 0; g < 4; ++g)
#pragma unroll
      for (int r = 0; r < 4; ++r)
        sP[wave][quad * 4 + r][g * 16 + l15] = (bf16)s[g][r];
    bf16x8 pf[2];
#pragma unroll
    for (int c = 0; c < 2; ++c)
      pf[c] = *(const bf16x8*)(&sP[wave][l15][c * 32 + quad * 8]);

#pragma unroll
    for (int c = 0; c < 2; ++c)
#pragma unroll
      for (int dg = 0; dg < 8; ++dg) {
        bf16x8 vf = *(const bf16x8*)(&sV[dg * 16 + l15][c * 32 + quad * 8]);
        of[dg] = __builtin_amdgcn_mfma_f32_16x16x32_bf16(pf[c], vf, of[dg], 0, 0, 0);
      }
    __syncthreads();
  }

  bf16* op = ctx + (size_t)(b * S_ + q0) * 2048 + h * 128;
#pragma unroll
  for (int r = 0; r < 4; ++r) {
    const float rl = 1.f / l4[r];
    const int row  = quad * 4 + r;
#pragma unroll
    for (int dg = 0; dg < 8; ++dg)
      op[(size_t)row * 2048 + dg * 16 + l15] = (bf16)(of[dg][r] * rl);
  }
}

// ---------------------------------------------------------------------------
// Workspace (bf16 elements, after 16-byte flag slot):
//   slotA [8.4M elems] : h (rms1) -> ctx (attn out) -> h2 (rms2)
//   slotB [8.4M]       : q -> x1 residual
//   slotC [2.1M]       : k
//   slotD [2.1M]       : v (natural)
//   slotE [33.6M]      : vT (first 4MB, dead before MLP) -> g (Wg/silu*u)
//   wT    [16.8M]      : per-weight bf16 B^T scratch (fast path only)
// ---------------------------------------------------------------------------
extern "C" void kernel_launch(void* const* d_in, const int* in_sizes, int n_in,
                              void* d_out, int out_size, void* d_ws, size_t ws_size,
                              hipStream_t stream) {
  (void)in_sizes; (void)n_in; (void)out_size;

  const void* hidden = d_in[0];
  const void* ln1 = d_in[3];
  const void* Wq  = d_in[4];
  const void* Wk  = d_in[5];
  const void* Wv  = d_in[6];
  const void* Wo  = d_in[7];
  const void* qn  = d_in[8];
  const void* kn  = d_in[9];
  const void* ln2 = d_in[10];
  const void* Wg  = d_in[11];
  const void* Wu  = d_in[12];
  const void* Wd  = d_in[13];

  int*  dtp   = (int*)d_ws;
  bf16* slotA = (bf16*)((char*)d_ws + 16);
  bf16* slotB = slotA + (size_t)M_ * 2048;
  bf16* slotC = slotB + (size_t)M_ * 2048;
  bf16* slotD = slotC + (size_t)M_ * 512;
  bf16* slotE = slotD + (size_t)M_ * 512;
  bf16* vT    = slotE;
  bf16* wT    = slotE + (size_t)M_ * 8192;

  const size_t need = 16 + 2ull * ((size_t)M_ * 2048 * 2 + (size_t)M_ * 512 * 2 +
                                   (size_t)M_ * 8192 + (size_t)I_ * H_);

  probe_k<<<1, 64, 0, stream>>>((const uint32*)hidden, dtp);
  rmsnorm_k<true><<<M_, 256, 0, stream>>>(hidden, ln1, slotA, dtp);

  if (ws_size >= need) {
    // ---- fast path: JIT bf16 B^T weights + 8-phase 256^2 GEMMs ----
    convert_wt<<<dim3(32, 32), 256, 0, stream>>>(Wq, wT, 2048, 2048, dtp);
    gemm8_k<0, false, false><<<dim3(8, 16), 512, 0, stream>>>(slotA, wT, slotB, nullptr, M_, 2048, 2048, dtp);
    convert_wt<<<dim3(8, 32), 256, 0, stream>>>(Wk, wT, 2048, 512, dtp);
    gemm_bt_k<0, false, false><<<dim3(4, 32), 256, 0, stream>>>(slotA, wT, slotC, nullptr, M_, 512, 2048, dtp);
    convert_wt<<<dim3(8, 32), 256, 0, stream>>>(Wv, wT, 2048, 512, dtp);
    gemm_bt_k<0, false, false><<<dim3(4, 32), 256, 0, stream>>>(slotA, wT, slotD, nullptr, M_, 512, 2048, dtp);
    transpose_v<<<dim3(8, 64), 256, 0, stream>>>(slotD, vT);
    rope_norm_k<<<(M_ * (NH_ + NKV_)) / 4, 256, 0, stream>>>(slotB, slotC, qn, kn, dtp);
    attn_mfma<<<B_ * NKV_ * (S_ / 16), 256, 0, stream>>>(slotB, slotC, vT, slotA);
    convert_wt<<<dim3(32, 32), 256, 0, stream>>>(Wo, wT, 2048, 2048, dtp);
    gemm8_k<1, true, false><<<dim3(8, 16), 512, 0, stream>>>(slotA, wT, slotB, hidden, M_, 2048, 2048, dtp);
    rmsnorm_k<false><<<M_, 256, 0, stream>>>(slotB, ln2, slotA, dtp);
    convert_wt<<<dim3(128, 32), 256, 0, stream>>>(Wg, wT, 2048, 8192, dtp);
    gemm8_k<0, false, false><<<dim3(32, 16), 512, 0, stream>>>(slotA, wT, slotE, nullptr, M_, 8192, 2048, dtp);
    convert_wt<<<dim3(128, 32), 256, 0, stream>>>(Wu, wT, 2048, 8192, dtp);
    gemm8_k<2, false, false><<<dim3(32, 16), 512, 0, stream>>>(slotA, wT, slotE, slotE, M_, 8192, 2048, dtp);
    convert_wt<<<dim3(32, 128), 256, 0, stream>>>(Wd, wT, 8192, 2048, dtp);
    gemm8_k<1, false, true><<<dim3(8, 16), 512, 0, stream>>>(slotE, wT, d_out, slotB, M_, 2048, 8192, dtp);
  } else {
    // ---- fallback: legacy in-GEMM conversion path (verified) ----
    gemm_k<0, false, false><<<dim3(16, 32), 256, 0, stream>>>(slotA, Wq, slotB, nullptr, M_, 2048, 2048, dtp);
    gemm_k<0, false, false><<<dim3(4, 32), 256, 0, stream>>>(slotA, Wk, slotC, nullptr, M_, 512, 2048, dtp);
    gemm_k<0, false, false><<<dim3(4, 32), 256, 0, stream>>>(slotA, Wv, slotD, nullptr, M_, 512, 2048, dtp);
    transpose_v<<<dim3(8, 64), 256, 0, stream>>>(slotD, vT);
    rope_norm_k<<<(M_ * (NH_ + NKV_)) / 4, 256, 0, stream>>>(slotB, slotC, qn, kn, dtp);
    attn_mfma<<<B_ * NKV_ * (S_ / 16), 256, 0, stream>>>(slotB, slotC, vT, slotA);
    gemm_k<1, true, false><<<dim3(16, 32), 256, 0, stream>>>(slotA, Wo, slotB, hidden, M_, 2048, 2048, dtp);
    rmsnorm_k<false><<<M_, 256, 0, stream>>>(slotB, ln2, slotA, dtp);
    gemm_k<0, false, false><<<dim3(64, 32), 256, 0, stream>>>(slotA, Wg, slotE, nullptr, M_, 8192, 2048, dtp);
    gemm_k<2, false, false><<<dim3(64, 32), 256, 0, stream>>>(slotA, Wu, slotE, slotE, M_, 8192, 2048, dtp);
    gemm_k<1, false, true><<<dim3(16, 32), 256, 0, stream>>>(slotE, Wd, d_out, slotB, M_, 2048, 8192, dtp);
  }
}

// Round 3
// 1216.020 us; speedup vs baseline: 2.3476x; 1.1674x over previous
//
#include <hip/hip_runtime.h>
#include <math.h>

typedef __bf16 bf16;
typedef bf16 bf16x8 __attribute__((ext_vector_type(8)));
typedef bf16 bf16x4 __attribute__((ext_vector_type(4)));
typedef float f32x4 __attribute__((ext_vector_type(4)));
typedef unsigned int uint32;

#define B_   2
#define S_   2048
#define H_   2048
#define NH_  16
#define NKV_ 4
#define HD_  128
#define I_   8192
#define M_   (B_ * S_)   // 4096 token rows

// ---------------------------------------------------------------------------
// async global->LDS, 16B per lane. Dest is wave-uniform base + lane*16.
// ---------------------------------------------------------------------------
typedef __attribute__((address_space(3))) void       lds_void;
typedef __attribute__((address_space(1))) const void gbl_void;

__device__ __forceinline__ void async16(const void* g, void* l) {
  __builtin_amdgcn_global_load_lds((gbl_void*)g, (lds_void*)l, 16, 0, 0);
}

// ---------------------------------------------------------------------------
// Dtype probe: raw inputs fp32 vs bf16 (verified: fp32 on this harness).
// ---------------------------------------------------------------------------
__global__ void probe_k(const uint32* __restrict__ x, int* __restrict__ flag) {
  const int lane = threadIdx.x;
  const uint32 u = x[lane];
  float blo = fabsf(__uint_as_float(u << 16));
  float bhi = fabsf(__uint_as_float(u & 0xffff0000u));
  float fv  = fabsf(__uint_as_float(u));
  if (!(blo < 1e30f)) blo = 3e38f;
  if (!(bhi < 1e30f)) bhi = 3e38f;
  if (!(fv  < 1e30f)) fv  = 3e38f;
  float mb = fmaxf(blo, bhi);
  float mf = fv;
#pragma unroll
  for (int off = 1; off < 64; off <<= 1) {
    mb = fmaxf(mb, __shfl_xor(mb, off, 64));
    mf = fmaxf(mf, __shfl_xor(mf, off, 64));
  }
  if (lane == 0) *flag = (mf < mb) ? 1 : 0;
}

// ---------------------------------------------------------------------------
// RMSNorm over H=2048 per row -> bf16 out.
// ---------------------------------------------------------------------------
template <bool INRAW>
__global__ __launch_bounds__(256) void rmsnorm_k(const void* __restrict__ xin,
                                                 const void* __restrict__ w,
                                                 bf16* __restrict__ out,
                                                 const int* __restrict__ dtp) {
  const int f    = *dtp;
  const int row  = blockIdx.x;
  const int tid  = threadIdx.x;
  const int base = row * H_ + tid * 8;

  float v[8];
  if (INRAW && f) {
    const float* xf = (const float*)xin + base;
    f32x4 a = *(const f32x4*)xf, b = *(const f32x4*)(xf + 4);
#pragma unroll
    for (int i = 0; i < 4; ++i) { v[i] = a[i]; v[4 + i] = b[i]; }
  } else {
    bf16x8 t = *(const bf16x8*)((const bf16*)xin + base);
#pragma unroll
    for (int i = 0; i < 8; ++i) v[i] = (float)t[i];
  }

  float ss = 0.f;
#pragma unroll
  for (int i = 0; i < 8; ++i) ss += v[i] * v[i];
#pragma unroll
  for (int off = 1; off < 64; off <<= 1) ss += __shfl_xor(ss, off, 64);

  __shared__ float red[4];
  if ((tid & 63) == 0) red[tid >> 6] = ss;
  __syncthreads();
  ss = red[0] + red[1] + red[2] + red[3];

  const float scale = rsqrtf(ss * (1.0f / H_) + 1e-6f);
  float wv[8];
  if (f) {
    const float* wf = (const float*)w + tid * 8;
    f32x4 a = *(const f32x4*)wf, b = *(const f32x4*)(wf + 4);
#pragma unroll
    for (int i = 0; i < 4; ++i) { wv[i] = a[i]; wv[4 + i] = b[i]; }
  } else {
    bf16x8 t = *(const bf16x8*)((const bf16*)w + tid * 8);
#pragma unroll
    for (int i = 0; i < 8; ++i) wv[i] = (float)t[i];
  }
  bf16x8 o;
#pragma unroll
  for (int i = 0; i < 8; ++i) o[i] = (bf16)(wv[i] * (v[i] * scale));
  *(bf16x8*)(out + base) = o;
}

// ---------------------------------------------------------------------------
// Weight convert+transpose: W (raw [K,N], fp32 or bf16 per dtp) -> bf16 Wt [N,K].
// ---------------------------------------------------------------------------
__global__ __launch_bounds__(256) void convert_wt(const void* __restrict__ W,
                                                  bf16* __restrict__ Wt,
                                                  const int K, const int N,
                                                  const int* __restrict__ dtp) {
  __shared__ bf16 sT[64][72];
  const int f   = *dtp;
  const int tid = threadIdx.x;
  const int k0  = blockIdx.y * 64;
  const int n0  = blockIdx.x * 64;
  if (f) {
#pragma unroll
    for (int p = 0; p < 4; ++p) {
      const int g  = tid + p * 256;
      const int r  = g >> 4;
      const int c4 = (g & 15) * 4;
      f32x4 v = *(const f32x4*)((const float*)W + (size_t)(k0 + r) * N + n0 + c4);
#pragma unroll
      for (int u = 0; u < 4; ++u) sT[c4 + u][r] = (bf16)v[u];
    }
  } else {
#pragma unroll
    for (int p = 0; p < 2; ++p) {
      const int g  = tid + p * 256;
      const int r  = g >> 3;
      const int c8 = (g & 7) * 8;
      bf16x8 v = *(const bf16x8*)((const bf16*)W + (size_t)(k0 + r) * N + n0 + c8);
#pragma unroll
      for (int u = 0; u < 8; ++u) sT[c8 + u][r] = v[u];
    }
  }
  __syncthreads();
#pragma unroll
  for (int p = 0; p < 2; ++p) {
    const int g  = tid + p * 256;
    const int n  = g >> 3;
    const int k8 = (g & 7) * 8;
    bf16x8 ov;
#pragma unroll
    for (int u = 0; u < 8; ++u) ov[u] = sT[n][k8 + u];
    *(bf16x8*)(Wt + (size_t)(n0 + n) * K + k0 + k8) = ov;
  }
}

// ---------------------------------------------------------------------------
// Split-K combine: C = epilogue(p0 + p1, aux). Vectorized x4.
// ---------------------------------------------------------------------------
template <int EPI, bool AUXRAW, bool CRAW>
__global__ __launch_bounds__(256) void combine_k(const float* __restrict__ p0,
                                                 const float* __restrict__ p1,
                                                 const void* __restrict__ aux,
                                                 void* __restrict__ C,
                                                 const size_t total,
                                                 const int* __restrict__ dtp) {
  const int f = *dtp;
  const size_t i = ((size_t)blockIdx.x * 256 + threadIdx.x) * 4;
  if (i >= total) return;
  f32x4 a = *(const f32x4*)(p0 + i);
  f32x4 b = *(const f32x4*)(p1 + i);
  float av4[4];
  if (EPI != 0) {
    if (AUXRAW && f) {
      f32x4 t = *(const f32x4*)((const float*)aux + i);
#pragma unroll
      for (int u = 0; u < 4; ++u) av4[u] = t[u];
    } else {
      bf16x4 t = *(const bf16x4*)((const bf16*)aux + i);
#pragma unroll
      for (int u = 0; u < 4; ++u) av4[u] = (float)t[u];
    }
  }
  float o[4];
#pragma unroll
  for (int u = 0; u < 4; ++u) {
    const float val = a[u] + b[u];
    if (EPI == 0) o[u] = val;
    else if (EPI == 1) o[u] = val + av4[u];
    else {
      const float sg = av4[u] / (1.f + __expf(-av4[u]));
      o[u] = sg * val;
    }
  }
  if (CRAW && f) {
    f32x4 ov; 
#pragma unroll
    for (int u = 0; u < 4; ++u) ov[u] = o[u];
    *(f32x4*)((float*)C + i) = ov;
  } else {
    bf16x4 ov;
#pragma unroll
    for (int u = 0; u < 4; ++u) ov[u] = (bf16)o[u];
    *(bf16x4*)((bf16*)C + i) = ov;
  }
}

// ---------------------------------------------------------------------------
// 256x256 8-phase GEMM (m201 template): C[M,N] = A[M,:] @ Bt[N,:]^T over a
// K-range. lda = leading dim (elements); loop runs K elements starting at
// blockIdx.z*K (split-K). EPI: 0 plain bf16; 1 acc+aux; 2 silu(aux)*acc;
// 3 fp32 partial to C + z*M*N (split-K). Counted vmcnt(6), setprio, swizzle.
// ---------------------------------------------------------------------------
#define BARX()  __builtin_amdgcn_s_barrier()
#define LGKM0() do { asm volatile("s_waitcnt lgkmcnt(0)" ::: "memory");       \
                     __builtin_amdgcn_sched_barrier(0); } while (0)
#define VMW6()  asm volatile("s_waitcnt vmcnt(6)" ::: "memory")

template <int EPI, bool AUXRAW, bool CRAW>
__global__ __launch_bounds__(512, 2) void gemm8_k(const bf16* __restrict__ A,
                                                  const bf16* __restrict__ Bt,
                                                  void* __restrict__ C,
                                                  const void* __restrict__ aux,
                                                  const int M, const int N,
                                                  const int K, const int lda,
                                                  const int* __restrict__ dtp) {
  __shared__ __align__(16) bf16 sA[2][256][64];   // 64 KiB
  __shared__ __align__(16) bf16 sB[2][256][64];   // 64 KiB

  const int f    = *dtp;
  const int tid  = threadIdx.x;
  const int lane = tid & 63;
  const int wave = tid >> 6;
  const int wr   = wave >> 2;    // 0..1
  const int wc   = wave & 3;     // 0..3
  const int l15  = lane & 15;
  const int quad = lane >> 4;

  // XCD-aware bijective swizzle (per z-slice; all grids used are %8==0)
  const int gx  = gridDim.x;
  const int nwg = gx * gridDim.y;
  int bid = blockIdx.y * gx + blockIdx.x;
  if ((nwg & 7) == 0) bid = (bid & 7) * (nwg >> 3) + (bid >> 3);
  const int row0 = (bid / gx) * 256;
  const int col0 = (bid % gx) * 256;
  const int koff = blockIdx.z * K;

  const int NT = K >> 6;   // K-tiles of 64

  // ---- fragment-read addressing (swizzled) ----
  const int swo = (l15 & 7) << 4;
  const int cb0 = (quad * 16) ^ swo;
  const int cb1 = (64 + quad * 16) ^ swo;
  char* sAc = (char*)&sA[0][0][0];
  char* sBc = (char*)&sB[0][0][0];

  // ---- staging source (inverse-swizzled global addr, linear LDS dest) ----
  const int d0   = tid * 16;
  const int d1   = 8192 + tid * 16;
  const int p0   = d0 ^ (((d0 >> 7) & 7) << 4);
  const int p1   = d1 ^ (((d1 >> 7) & 7) << 4);
  const int rg0  = p0 >> 7, cbs0 = p0 & 127;
  const int rg1  = p1 >> 7, cbs1 = p1 & 127;
  const size_t LD2 = (size_t)lda * 2;
  const char* gA = (const char*)A  + (size_t)row0 * LD2 + (size_t)koff * 2;
  const char* gB = (const char*)Bt + (size_t)col0 * LD2 + (size_t)koff * 2;

#define STAGE8(gbase, sbase, s, h, t) do {                                     \
    const int tt_ = ((t) < NT) ? (t) : ((t) - NT);                             \
    const size_t go_ = (size_t)tt_ * 128;                                      \
    async16(gbase + (size_t)((h) * 128 + rg0) * LD2 + go_ + cbs0,              \
            (sbase) + (s) * 32768 + (h) * 16384 + tid * 16);                   \
    async16(gbase + (size_t)((h) * 128 + rg1) * LD2 + go_ + cbs1,              \
            (sbase) + (s) * 32768 + (h) * 16384 + 8192 + tid * 16);            \
  } while (0)
#define STA(s, h, t) STAGE8(gA, sAc, s, h, t)
#define STB(s, h, t) STAGE8(gB, sBc, s, h, t)

  bf16x8 af[4][2], bfr[2][2];
  f32x4 acc[8][4];
#pragma unroll
  for (int m = 0; m < 8; ++m)
#pragma unroll
    for (int n = 0; n < 4; ++n)
#pragma unroll
      for (int r = 0; r < 4; ++r) acc[m][n][r] = 0.f;

#define LDA8(s, mh) do {                                                       \
    _Pragma("unroll")                                                          \
    for (int mi = 0; mi < 4; ++mi) {                                           \
      const int rb = ((mh) * 128 + wr * 64 + mi * 16 + l15) * 128;             \
      af[mi][0] = *(const bf16x8*)(sAc + (s) * 32768 + rb + cb0);              \
      af[mi][1] = *(const bf16x8*)(sAc + (s) * 32768 + rb + cb1);              \
    }                                                                          \
  } while (0)

#define LDB8(s, nh) do {                                                       \
    _Pragma("unroll")                                                          \
    for (int ni = 0; ni < 2; ++ni) {                                           \
      const int rb = ((nh) * 128 + wc * 32 + ni * 16 + l15) * 128;             \
      bfr[ni][0] = *(const bf16x8*)(sBc + (s) * 32768 + rb + cb0);             \
      bfr[ni][1] = *(const bf16x8*)(sBc + (s) * 32768 + rb + cb1);             \
    }                                                                          \
  } while (0)

#define MFMA16(mh, nh) do {                                                    \
    __builtin_amdgcn_s_setprio(1);                                             \
    _Pragma("unroll")                                                          \
    for (int mi = 0; mi < 4; ++mi)                                             \
      _Pragma("unroll")                                                        \
      for (int ni = 0; ni < 2; ++ni) {                                         \
        acc[(mh)*4+mi][(nh)*2+ni] = __builtin_amdgcn_mfma_f32_16x16x32_bf16(   \
            af[mi][0], bfr[ni][0], acc[(mh)*4+mi][(nh)*2+ni], 0, 0, 0);        \
        acc[(mh)*4+mi][(nh)*2+ni] = __builtin_amdgcn_mfma_f32_16x16x32_bf16(   \
            af[mi][1], bfr[ni][1], acc[(mh)*4+mi][(nh)*2+ni], 0, 0, 0);        \
      }                                                                        \
    __builtin_amdgcn_s_setprio(0);                                             \
  } while (0)

  // ---- prologue: tile0 full + 3 halves of tile1; tile0 landed ----
  STA(0, 0, 0); STA(0, 1, 0); STB(0, 0, 0); STB(0, 1, 0);
  STA(1, 0, 1); STA(1, 1, 1); STB(1, 0, 1);
  VMW6();
  BARX();

#pragma unroll 1
  for (int T = 0; T < NT; T += 2) {
    // ph1: tile T quad(0,0); stage hB1(T+1)->buf1
    LDA8(0, 0); LDB8(0, 0);
    STB(1, 1, T + 1);
    BARX(); LGKM0(); MFMA16(0, 0); BARX();
    // ph2: quad(0,1); stage hA0(T+2)->buf0
    LDB8(0, 1);
    STA(0, 0, T + 2);
    BARX(); LGKM0(); MFMA16(0, 1); BARX();
    // ph3: quad(1,0)
    LDA8(0, 1); LDB8(0, 0);
    BARX(); LGKM0(); MFMA16(1, 0); BARX();
    // ph4: quad(1,1); stage hA1,hB0(T+2); vmcnt(6) -> tile T+1 landed
    LDB8(0, 1);
    STA(0, 1, T + 2); STB(0, 0, T + 2);
    BARX(); LGKM0(); MFMA16(1, 1); VMW6(); BARX();
    // ph5: tile T+1 quad(0,0); stage hB1(T+2)->buf0
    LDA8(1, 0); LDB8(1, 0);
    STB(0, 1, T + 2);
    BARX(); LGKM0(); MFMA16(0, 0); BARX();
    // ph6: quad(0,1); stage hA0(T+3)->buf1
    LDB8(1, 1);
    STA(1, 0, T + 3);
    BARX(); LGKM0(); MFMA16(0, 1); BARX();
    // ph7: quad(1,0)
    LDA8(1, 1); LDB8(1, 0);
    BARX(); LGKM0(); MFMA16(1, 0); BARX();
    // ph8: quad(1,1); stage hA1,hB0(T+3); vmcnt(6) -> tile T+2 landed
    LDB8(1, 1);
    STA(1, 1, T + 3); STB(1, 0, T + 3);
    BARX(); LGKM0(); MFMA16(1, 1); VMW6(); BARX();
  }
  asm volatile("s_waitcnt vmcnt(0)" ::: "memory");

  // ---- epilogue ----
  float* P = (EPI == 3)
      ? (float*)C + (size_t)blockIdx.z * ((size_t)M * N) : nullptr;
#pragma unroll
  for (int m = 0; m < 8; ++m) {
#pragma unroll
    for (int n = 0; n < 4; ++n) {
#pragma unroll
      for (int r = 0; r < 4; ++r) {
        const int row = row0 + (m >> 2) * 128 + wr * 64 + (m & 3) * 16 + quad * 4 + r;
        const int col = col0 + (n >> 1) * 128 + wc * 32 + (n & 1) * 16 + l15;
        const size_t idx = (size_t)row * N + col;
        const float val  = acc[m][n][r];
        if (EPI == 3) {
          P[idx] = val;
        } else {
          float outv;
          if (EPI == 0) {
            outv = val;
          } else {
            const float av = (AUXRAW && f) ? ((const float*)aux)[idx]
                                           : (float)((const bf16*)aux)[idx];
            if (EPI == 1) {
              outv = val + av;
            } else {
              const float sg = av / (1.f + __expf(-av));
              outv = sg * val;
            }
          }
          if (CRAW && f) ((float*)C)[idx] = outv;
          else           ((bf16*)C)[idx]  = (bf16)outv;
        }
      }
    }
  }
#undef STAGE8
#undef STA
#undef STB
#undef LDA8
#undef LDB8
#undef MFMA16
}

// ---------------------------------------------------------------------------
// 2-phase 128x128 GEMM (verified m97 structure). lda/split-K like gemm8_k.
// EPI 3 = fp32 partial to C + z*M*N.
// ---------------------------------------------------------------------------
template <int EPI, bool AUXRAW, bool CRAW>
__global__ __launch_bounds__(256) void gemm_bt_k(const bf16* __restrict__ A,
                                                 const bf16* __restrict__ Bt,
                                                 void* __restrict__ C,
                                                 const void* __restrict__ aux,
                                                 const int M, const int N,
                                                 const int K, const int lda,
                                                 const int* __restrict__ dtp) {
  __shared__ __align__(16) bf16 sA[128][32];
  __shared__ __align__(16) bf16 sB[128][32];

  const int f    = *dtp;
  const int tid  = threadIdx.x;
  const int lane = tid & 63;
  const int wave = tid >> 6;
  const int wm   = (wave >> 1) * 64;
  const int wn   = (wave & 1) * 64;
  const int row0 = blockIdx.y * 128;
  const int col0 = blockIdx.x * 128;
  const int koff = blockIdx.z * K;
  const int l15  = lane & 15;
  const int quad = lane >> 4;

  f32x4 acc[4][4];
#pragma unroll
  for (int i = 0; i < 4; ++i)
#pragma unroll
    for (int j = 0; j < 4; ++j)
#pragma unroll
      for (int r = 0; r < 4; ++r) acc[i][j][r] = 0.f;

  const int o  = tid * 16;
  const int r0 = o >> 6;
  const int ib = o & 63;

  const char* gA0 = (const char*)(A  + (size_t)(row0 + r0)      * lda + koff) + ib;
  const char* gA1 = (const char*)(A  + (size_t)(row0 + 64 + r0) * lda + koff) + ib;
  const char* gB0 = (const char*)(Bt + (size_t)(col0 + r0)      * lda + koff) + ib;
  const char* gB1 = (const char*)(Bt + (size_t)(col0 + 64 + r0) * lda + koff) + ib;
  char* lA = (char*)(&sA[0][0]) + wave * 1024;
  char* lB = (char*)(&sB[0][0]) + wave * 1024;

  for (int k0 = 0; k0 < K; k0 += 32) {
    async16(gA0, lA);
    async16(gA1, lA + 4096);
    async16(gB0, lB);
    async16(gB1, lB + 4096);
    gA0 += 64; gA1 += 64; gB0 += 64; gB1 += 64;
    __syncthreads();

    bf16x8 af[4], bfr[4];
#pragma unroll
    for (int i = 0; i < 4; ++i)
      af[i] = *(const bf16x8*)(&sA[wm + i * 16 + l15][quad * 8]);
#pragma unroll
    for (int j = 0; j < 4; ++j)
      bfr[j] = *(const bf16x8*)(&sB[wn + j * 16 + l15][quad * 8]);
#pragma unroll
    for (int i = 0; i < 4; ++i)
#pragma unroll
      for (int j = 0; j < 4; ++j)
        acc[i][j] = __builtin_amdgcn_mfma_f32_16x16x32_bf16(af[i], bfr[j],
                                                            acc[i][j], 0, 0, 0);
    __syncthreads();
  }

  float* P = (EPI == 3)
      ? (float*)C + (size_t)blockIdx.z * ((size_t)M * N) : nullptr;
#pragma unroll
  for (int i = 0; i < 4; ++i) {
#pragma unroll
    for (int j = 0; j < 4; ++j) {
#pragma unroll
      for (int r = 0; r < 4; ++r) {
        const int row    = row0 + wm + i * 16 + quad * 4 + r;
        const int col    = col0 + wn + j * 16 + l15;
        const size_t idx = (size_t)row * N + col;
        const float val  = acc[i][j][r];
        if (EPI == 3) {
          P[idx] = val;
        } else {
          float outv;
          if (EPI == 0) {
            outv = val;
          } else {
            const float av = (AUXRAW && f) ? ((const float*)aux)[idx]
                                           : (float)((const bf16*)aux)[idx];
            if (EPI == 1) {
              outv = val + av;
            } else {
              const float sg = av / (1.f + __expf(-av));
              outv = sg * val;
            }
          }
          if (CRAW && f) ((float*)C)[idx] = outv;
          else           ((bf16*)C)[idx]  = (bf16)outv;
        }
      }
    }
  }
}

// ---------------------------------------------------------------------------
// Legacy GEMM (fallback when workspace can't hold the B^T scratch).
// ---------------------------------------------------------------------------
template <int EPI, bool AUXRAW, bool CRAW>
__global__ __launch_bounds__(256) void gemm_k(const bf16* __restrict__ A,
                                              const void* __restrict__ Bm,
                                              void* __restrict__ C,
                                              const void* __restrict__ aux,
                                              const int M, const int N, const int K,
                                              const int* __restrict__ dtp) {
  __shared__ __align__(16) bf16 sA[128][40];
  __shared__ __align__(16) bf16 sB[128][40];

  const int f    = *dtp;
  const int tid  = threadIdx.x;
  const int lane = tid & 63;
  const int wave = tid >> 6;
  const int wm   = (wave >> 1) * 64;
  const int wn   = (wave & 1) * 64;
  const int row0 = blockIdx.y * 128;
  const int col0 = blockIdx.x * 128;
  const int l15  = lane & 15;
  const int quad = lane >> 4;

  f32x4 acc[4][4];
#pragma unroll
  for (int i = 0; i < 4; ++i)
#pragma unroll
    for (int j = 0; j < 4; ++j)
#pragma unroll
      for (int r = 0; r < 4; ++r) acc[i][j][r] = 0.f;

  for (int k0 = 0; k0 < K; k0 += 32) {
#pragma unroll
    for (int pass = 0; pass < 2; ++pass) {
      const int g  = tid + pass * 256;
      const int ar = g >> 2, ac = (g & 3) * 8;
      *(bf16x8*)(&sA[ar][ac]) =
          *(const bf16x8*)(A + (size_t)(row0 + ar) * K + k0 + ac);
      const int br = g >> 4, bc = (g & 15) * 8;
      const size_t boff = (size_t)(k0 + br) * N + col0 + bc;
      bf16x8 bv;
      if (f) {
        const float* bp = (const float*)Bm + boff;
        f32x4 lo = *(const f32x4*)bp, hi = *(const f32x4*)(bp + 4);
#pragma unroll
        for (int u = 0; u < 8; ++u) bv[u] = (bf16)(u < 4 ? lo[u] : hi[u - 4]);
      } else {
        bv = *(const bf16x8*)((const bf16*)Bm + boff);
      }
#pragma unroll
      for (int u = 0; u < 8; ++u) sB[bc + u][br] = bv[u];
    }
    __syncthreads();

    bf16x8 af[4], bfr[4];
#pragma unroll
    for (int i = 0; i < 4; ++i)
      af[i] = *(const bf16x8*)(&sA[wm + i * 16 + l15][quad * 8]);
#pragma unroll
    for (int j = 0; j < 4; ++j)
      bfr[j] = *(const bf16x8*)(&sB[wn + j * 16 + l15][quad * 8]);
#pragma unroll
    for (int i = 0; i < 4; ++i)
#pragma unroll
      for (int j = 0; j < 4; ++j)
        acc[i][j] = __builtin_amdgcn_mfma_f32_16x16x32_bf16(af[i], bfr[j],
                                                            acc[i][j], 0, 0, 0);
    __syncthreads();
  }

#pragma unroll
  for (int i = 0; i < 4; ++i) {
#pragma unroll
    for (int j = 0; j < 4; ++j) {
#pragma unroll
      for (int r = 0; r < 4; ++r) {
        const int row    = row0 + wm + i * 16 + quad * 4 + r;
        const int col    = col0 + wn + j * 16 + l15;
        const size_t idx = (size_t)row * N + col;
        const float val  = acc[i][j][r];
        float outv;
        if (EPI == 0) {
          outv = val;
        } else {
          const float av = (AUXRAW && f) ? ((const float*)aux)[idx]
                                         : (float)((const bf16*)aux)[idx];
          if (EPI == 1) {
            outv = val + av;
          } else {
            const float sg = av / (1.f + __expf(-av));
            outv = sg * val;
          }
        }
        if (CRAW && f) ((float*)C)[idx] = outv;
        else           ((bf16*)C)[idx]  = (bf16)outv;
      }
    }
  }
}

// ---------------------------------------------------------------------------
// RoPE + QK-RMSNorm, in place on q [M,2048] and k [M,512].
// ---------------------------------------------------------------------------
__global__ __launch_bounds__(256) void rope_norm_k(bf16* __restrict__ q,
                                                   bf16* __restrict__ k,
                                                   const void* __restrict__ qw,
                                                   const void* __restrict__ kw,
                                                   const int* __restrict__ dtp) {
  const int f    = *dtp;
  const int task = blockIdx.x * 4 + (threadIdx.x >> 6);
  const int lane = threadIdx.x & 63;
  const int row  = task / 20;
  const int hh   = task - row * 20;

  bf16* p;
  const void* w;
  if (hh < NH_) { p = q + (size_t)row * 2048 + hh * 128;        w = qw; }
  else          { p = k + (size_t)row * 512 + (hh - NH_) * 128; w = kw; }

  const float pos = (float)(row & (S_ - 1));
  const float inv = powf(10000.f, -(float)lane * (1.f / 64.f));
  float sn, cs;
  sincosf(pos * inv, &sn, &cs);

  const float x0 = (float)p[lane], x1 = (float)p[lane + 64];
  const float r0 = x0 * cs - x1 * sn;
  const float r1 = x1 * cs + x0 * sn;

  float ss = r0 * r0 + r1 * r1;
#pragma unroll
  for (int off = 1; off < 64; off <<= 1) ss += __shfl_xor(ss, off, 64);
  const float scale = rsqrtf(ss * (1.f / 128.f) + 1e-6f);

  const float w0 = f ? ((const float*)w)[lane]      : (float)((const bf16*)w)[lane];
  const float w1 = f ? ((const float*)w)[lane + 64] : (float)((const bf16*)w)[lane + 64];
  p[lane]      = (bf16)(w0 * (r0 * scale));
  p[lane + 64] = (bf16)(w1 * (r1 * scale));
}

// ---------------------------------------------------------------------------
// V transpose: v [M,512] -> vt [B][512][S].
// ---------------------------------------------------------------------------
__global__ __launch_bounds__(256) void transpose_v(const bf16* __restrict__ v,
                                                   bf16* __restrict__ vt) {
  __shared__ bf16 sT[64][68];
  const int tid = threadIdx.x;
  const int r0  = blockIdx.y * 64;
  const int c0  = blockIdx.x * 64;
  const int b   = r0 >> 11;
  const int s0  = r0 & 2047;
#pragma unroll
  for (int p = 0; p < 2; ++p) {
    const int g   = tid + p * 256;
    const int row = g >> 3;
    const int c8  = (g & 7) * 8;
    bf16x8 tv = *(const bf16x8*)(v + (size_t)(r0 + row) * 512 + c0 + c8);
#pragma unroll
    for (int u = 0; u < 8; ++u) sT[c8 + u][row] = tv[u];
  }
  __syncthreads();
#pragma unroll
  for (int p = 0; p < 2; ++p) {
    const int g  = tid + p * 256;
    const int oc = g >> 3;
    const int s8 = (g & 7) * 8;
    bf16x8 ov;
#pragma unroll
    for (int u = 0; u < 8; ++u) ov[u] = sT[oc][s8 + u];
    *(bf16x8*)(vt + ((size_t)(b * 512 + c0 + oc)) * 2048 + s0 + s8) = ov;
  }
}

// ---------------------------------------------------------------------------
// MFMA flash attention (causal, GQA). Unchanged from verified kernel.
// ---------------------------------------------------------------------------
__global__ __launch_bounds__(256) void attn_mfma(const bf16* __restrict__ q,
                                                 const bf16* __restrict__ k,
                                                 const bf16* __restrict__ vt,
                                                 bf16* __restrict__ ctx) {
  __shared__ __align__(16) bf16 sK[64][136];
  __shared__ __align__(16) bf16 sV[128][72];
  __shared__ __align__(16) bf16 sP[4][16][72];

  const int tid  = threadIdx.x;
  const int lane = tid & 63;
  const int wave = tid >> 6;
  const int l15  = lane & 15;
  const int quad = lane >> 4;

  const int bid = blockIdx.x;
  const int i7  = bid & 127;
  const int qt  = (i7 & 1) ? (127 - (i7 >> 1)) : (i7 >> 1);
  const int kvh = (bid >> 7) & 3;
  const int b   = bid >> 9;
  const int q0  = qt * 16;
  const int h   = kvh * 4 + wave;

  bf16x8 qf[4];
  {
    const bf16* qp = q + (size_t)(b * S_ + q0 + l15) * 2048 + h * 128 + quad * 8;
#pragma unroll
    for (int c = 0; c < 4; ++c) qf[c] = *(const bf16x8*)(qp + c * 32);
  }

  float m4[4], l4[4];
  f32x4 of[8];
#pragma unroll
  for (int r = 0; r < 4; ++r) { m4[r] = -1e30f; l4[r] = 0.f; }
#pragma unroll
  for (int dg = 0; dg < 8; ++dg)
#pragma unroll
    for (int r = 0; r < 4; ++r) of[dg][r] = 0.f;

  const int ntiles = (q0 + 16 + 63) >> 6;
  const bf16* kbase = k + (size_t)b * S_ * 512 + kvh * 128;
  const bf16* vbase = vt + (size_t)(b * 512 + kvh * 128) * 2048;
  const float sc = 0.088388347648318447f;

  for (int t = 0; t < ntiles; ++t) {
    const int j0 = t << 6;
#pragma unroll
    for (int p = 0; p < 4; ++p) {
      const int g   = tid + p * 256;
      const int dc  = g & 15;
      const int key = g >> 4;
      *(bf16x8*)(&sK[key][dc * 8]) =
          *(const bf16x8*)(kbase + (size_t)(j0 + key) * 512 + dc * 8);
    }
#pragma unroll
    for (int p = 0; p < 4; ++p) {
      const int g   = tid + p * 256;
      const int dim = g >> 3;
      const int k8  = (g & 7) * 8;
      *(bf16x8*)(&sV[dim][k8]) =
          *(const bf16x8*)(vbase + (size_t)dim * 2048 + j0 + k8);
    }
    __syncthreads();

    f32x4 sa[4];
#pragma unroll
    for (int g = 0; g < 4; ++g)
#pragma unroll
      for (int r = 0; r < 4; ++r) sa[g][r] = 0.f;
#pragma unroll
    for (int g = 0; g < 4; ++g)
#pragma unroll
      for (int c = 0; c < 4; ++c) {
        bf16x8 kf = *(const bf16x8*)(&sK[g * 16 + l15][c * 32 + quad * 8]);
        sa[g] = __builtin_amdgcn_mfma_f32_16x16x32_bf16(qf[c], kf, sa[g], 0, 0, 0);
      }

    float s[4][4];
    const bool mask = (t == ntiles - 1);
#pragma unroll
    for (int g = 0; g < 4; ++g)
#pragma unroll
      for (int r = 0; r < 4; ++r) {
        float x = sa[g][r] * sc;
        if (mask && (j0 + g * 16 + l15 > q0 + quad * 4 + r)) x = -1e30f;
        s[g][r] = x;
      }

    float al[4];
#pragma unroll
    for (int r = 0; r < 4; ++r) {
      float rm = fmaxf(fmaxf(s[0][r], s[1][r]), fmaxf(s[2][r], s[3][r]));
#pragma unroll
      for (int off = 1; off < 16; off <<= 1) rm = fmaxf(rm, __shfl_xor(rm, off, 64));
      const float mn = fmaxf(m4[r], rm);
      al[r] = __expf(m4[r] - mn);
      float rs = 0.f;
#pragma unroll
      for (int g = 0; g < 4; ++g) { s[g][r] = __expf(s[g][r] - mn); rs += s[g][r]; }
#pragma unroll
      for (int off = 1; off < 16; off <<= 1) rs += __shfl_xor(rs, off, 64);
      l4[r] = l4[r] * al[r] + rs;
      m4[r] = mn;
    }
#pragma unroll
    for (int dg = 0; dg < 8; ++dg)
#pragma unroll
      for (int r = 0; r < 4; ++r) of[dg][r] *= al[r];

#pragma unroll
    for (int g = 0; g < 4; ++g)
#pragma unroll
      for (int r = 0; r < 4; ++r)
        sP[wave][quad * 4 + r][g * 16 + l15] = (bf16)s[g][r];
    bf16x8 pf[2];
#pragma unroll
    for (int c = 0; c < 2; ++c)
      pf[c] = *(const bf16x8*)(&sP[wave][l15][c * 32 + quad * 8]);

#pragma unroll
    for (int c = 0; c < 2; ++c)
#pragma unroll
      for (int dg = 0; dg < 8; ++dg) {
        bf16x8 vf = *(const bf16x8*)(&sV[dg * 16 + l15][c * 32 + quad * 8]);
        of[dg] = __builtin_amdgcn_mfma_f32_16x16x32_bf16(pf[c], vf, of[dg], 0, 0, 0);
      }
    __syncthreads();
  }

  bf16* op = ctx + (size_t)(b * S_ + q0) * 2048 + h * 128;
#pragma unroll
  for (int r = 0; r < 4; ++r) {
    const float rl = 1.f / l4[r];
    const int row  = quad * 4 + r;
#pragma unroll
    for (int dg = 0; dg < 8; ++dg)
      op[(size_t)row * 2048 + dg * 16 + l15] = (bf16)(of[dg][r] * rl);
  }
}

// ---------------------------------------------------------------------------
// Workspace (bf16 elements, after 16-byte flag slot):
//   slotA [8.4M] slotB [8.4M] slotC [2.1M] slotD [2.1M] slotE [33.6M]
//   wT [16.8M]  (B^T scratch, tier >= 1)
//   slotP [2 x 8.4M floats = 67MB]  (split-K partials, tier 2 only)
// ---------------------------------------------------------------------------
extern "C" void kernel_launch(void* const* d_in, const int* in_sizes, int n_in,
                              void* d_out, int out_size, void* d_ws, size_t ws_size,
                              hipStream_t stream) {
  (void)in_sizes; (void)n_in; (void)out_size;

  const void* hidden = d_in[0];
  const void* ln1 = d_in[3];
  const void* Wq  = d_in[4];
  const void* Wk  = d_in[5];
  const void* Wv  = d_in[6];
  const void* Wo  = d_in[7];
  const void* qn  = d_in[8];
  const void* kn  = d_in[9];
  const void* ln2 = d_in[10];
  const void* Wg  = d_in[11];
  const void* Wu  = d_in[12];
  const void* Wd  = d_in[13];

  int*  dtp   = (int*)d_ws;
  bf16* slotA = (bf16*)((char*)d_ws + 16);
  bf16* slotB = slotA + (size_t)M_ * 2048;
  bf16* slotC = slotB + (size_t)M_ * 2048;
  bf16* slotD = slotC + (size_t)M_ * 512;
  bf16* slotE = slotD + (size_t)M_ * 512;
  bf16* vT    = slotE;
  bf16* wT    = slotE + (size_t)M_ * 8192;
  float* pP   = (float*)(wT + (size_t)I_ * H_);
  float* pP1  = pP + (size_t)M_ * 2048;

  const size_t need1 = 16 + 2ull * ((size_t)M_ * 2048 * 2 + (size_t)M_ * 512 * 2 +
                                    (size_t)M_ * 8192 + (size_t)I_ * H_);
  const size_t need2 = need1 + 2ull * (size_t)M_ * 2048 * 4;

  probe_k<<<1, 64, 0, stream>>>((const uint32*)hidden, dtp);
  rmsnorm_k<true><<<M_, 256, 0, stream>>>(hidden, ln1, slotA, dtp);

  if (ws_size >= need2) {
    // ---- tier 2: split-K for the N<=2048 GEMMs (full-GPU grids) ----
    convert_wt<<<dim3(32, 32), 256, 0, stream>>>(Wq, wT, 2048, 2048, dtp);
    gemm8_k<3, false, false><<<dim3(8, 16, 2), 512, 0, stream>>>(slotA, wT, pP, nullptr, M_, 2048, 1024, 2048, dtp);
    combine_k<0, false, false><<<(M_ * 2048) / 1024, 256, 0, stream>>>(pP, pP1, nullptr, slotB, (size_t)M_ * 2048, dtp);
    convert_wt<<<dim3(8, 32), 256, 0, stream>>>(Wk, wT, 2048, 512, dtp);
    gemm_bt_k<3, false, false><<<dim3(4, 32, 2), 256, 0, stream>>>(slotA, wT, pP, nullptr, M_, 512, 1024, 2048, dtp);
    combine_k<0, false, false><<<(M_ * 512) / 1024, 256, 0, stream>>>(pP, pP + (size_t)M_ * 512, nullptr, slotC, (size_t)M_ * 512, dtp);
    convert_wt<<<dim3(8, 32), 256, 0, stream>>>(Wv, wT, 2048, 512, dtp);
    gemm_bt_k<3, false, false><<<dim3(4, 32, 2), 256, 0, stream>>>(slotA, wT, pP, nullptr, M_, 512, 1024, 2048, dtp);
    combine_k<0, false, false><<<(M_ * 512) / 1024, 256, 0, stream>>>(pP, pP + (size_t)M_ * 512, nullptr, slotD, (size_t)M_ * 512, dtp);
    transpose_v<<<dim3(8, 64), 256, 0, stream>>>(slotD, vT);
    rope_norm_k<<<(M_ * (NH_ + NKV_)) / 4, 256, 0, stream>>>(slotB, slotC, qn, kn, dtp);
    attn_mfma<<<B_ * NKV_ * (S_ / 16), 256, 0, stream>>>(slotB, slotC, vT, slotA);
    convert_wt<<<dim3(32, 32), 256, 0, stream>>>(Wo, wT, 2048, 2048, dtp);
    gemm8_k<3, false, false><<<dim3(8, 16, 2), 512, 0, stream>>>(slotA, wT, pP, nullptr, M_, 2048, 1024, 2048, dtp);
    combine_k<1, true, false><<<(M_ * 2048) / 1024, 256, 0, stream>>>(pP, pP1, hidden, slotB, (size_t)M_ * 2048, dtp);
    rmsnorm_k<false><<<M_, 256, 0, stream>>>(slotB, ln2, slotA, dtp);
    convert_wt<<<dim3(128, 32), 256, 0, stream>>>(Wg, wT, 2048, 8192, dtp);
    gemm8_k<0, false, false><<<dim3(32, 16), 512, 0, stream>>>(slotA, wT, slotE, nullptr, M_, 8192, 2048, 2048, dtp);
    convert_wt<<<dim3(128, 32), 256, 0, stream>>>(Wu, wT, 2048, 8192, dtp);
    gemm8_k<2, false, false><<<dim3(32, 16), 512, 0, stream>>>(slotA, wT, slotE, slotE, M_, 8192, 2048, 2048, dtp);
    convert_wt<<<dim3(32, 128), 256, 0, stream>>>(Wd, wT, 8192, 2048, dtp);
    gemm8_k<3, false, false><<<dim3(8, 16, 2), 512, 0, stream>>>(slotE, wT, pP, nullptr, M_, 2048, 4096, 8192, dtp);
    combine_k<1, false, true><<<(M_ * 2048) / 1024, 256, 0, stream>>>(pP, pP1, slotB, d_out, (size_t)M_ * 2048, dtp);
  } else if (ws_size >= need1) {
    // ---- tier 1: round-2 path (no split-K scratch) ----
    convert_wt<<<dim3(32, 32), 256, 0, stream>>>(Wq, wT, 2048, 2048, dtp);
    gemm8_k<0, false, false><<<dim3(8, 16), 512, 0, stream>>>(slotA, wT, slotB, nullptr, M_, 2048, 2048, 2048, dtp);
    convert_wt<<<dim3(8, 32), 256, 0, stream>>>(Wk, wT, 2048, 512, dtp);
    gemm_bt_k<0, false, false><<<dim3(4, 32), 256, 0, stream>>>(slotA, wT, slotC, nullptr, M_, 512, 2048, 2048, dtp);
    convert_wt<<<dim3(8, 32), 256, 0, stream>>>(Wv, wT, 2048, 512, dtp);
    gemm_bt_k<0, false, false><<<dim3(4, 32), 256, 0, stream>>>(slotA, wT, slotD, nullptr, M_, 512, 2048, 2048, dtp);
    transpose_v<<<dim3(8, 64), 256, 0, stream>>>(slotD, vT);
    rope_norm_k<<<(M_ * (NH_ + NKV_)) / 4, 256, 0, stream>>>(slotB, slotC, qn, kn, dtp);
    attn_mfma<<<B_ * NKV_ * (S_ / 16), 256, 0, stream>>>(slotB, slotC, vT, slotA);
    convert_wt<<<dim3(32, 32), 256, 0, stream>>>(Wo, wT, 2048, 2048, dtp);
    gemm8_k<1, true, false><<<dim3(8, 16), 512, 0, stream>>>(slotA, wT, slotB, hidden, M_, 2048, 2048, 2048, dtp);
    rmsnorm_k<false><<<M_, 256, 0, stream>>>(slotB, ln2, slotA, dtp);
    convert_wt<<<dim3(128, 32), 256, 0, stream>>>(Wg, wT, 2048, 8192, dtp);
    gemm8_k<0, false, false><<<dim3(32, 16), 512, 0, stream>>>(slotA, wT, slotE, nullptr, M_, 8192, 2048, 2048, dtp);
    convert_wt<<<dim3(128, 32), 256, 0, stream>>>(Wu, wT, 2048, 8192, dtp);
    gemm8_k<2, false, false><<<dim3(32, 16), 512, 0, stream>>>(slotA, wT, slotE, slotE, M_, 8192, 2048, 2048, dtp);
    convert_wt<<<dim3(32, 128), 256, 0, stream>>>(Wd, wT, 8192, 2048, dtp);
    gemm8_k<1, false, true><<<dim3(8, 16), 512, 0, stream>>>(slotE, wT, d_out, slotB, M_, 2048, 8192, 8192, dtp);
  } else {
    // ---- fallback: legacy in-GEMM conversion path (verified) ----
    gemm_k<0, false, false><<<dim3(16, 32), 256, 0, stream>>>(slotA, Wq, slotB, nullptr, M_, 2048, 2048, dtp);
    gemm_k<0, false, false><<<dim3(4, 32), 256, 0, stream>>>(slotA, Wk, slotC, nullptr, M_, 512, 2048, dtp);
    gemm_k<0, false, false><<<dim3(4, 32), 256, 0, stream>>>(slotA, Wv, slotD, nullptr, M_, 512, 2048, dtp);
    transpose_v<<<dim3(8, 64), 256, 0, stream>>>(slotD, vT);
    rope_norm_k<<<(M_ * (NH_ + NKV_)) / 4, 256, 0, stream>>>(slotB, slotC, qn, kn, dtp);
    attn_mfma<<<B_ * NKV_ * (S_ / 16), 256, 0, stream>>>(slotB, slotC, vT, slotA);
    gemm_k<1, true, false><<<dim3(16, 32), 256, 0, stream>>>(slotA, Wo, slotB, hidden, M_, 2048, 2048, dtp);
    rmsnorm_k<false><<<M_, 256, 0, stream>>>(slotB, ln2, slotA, dtp);
    gemm_k<0, false, false><<<dim3(64, 32), 256, 0, stream>>>(slotA, Wg, slotE, nullptr, M_, 8192, 2048, dtp);
    gemm_k<2, false, false><<<dim3(64, 32), 256, 0, stream>>>(slotA, Wu, slotE, slotE, M_, 8192, 2048, dtp);
    gemm_k<1, false, true><<<dim3(16, 32), 256, 0, stream>>>(slotE, Wd, d_out, slotB, M_, 2048, 8192, dtp);
  }
}

// Round 6
// 1213.498 us; speedup vs baseline: 2.3525x; 1.0021x over previous
//
#include <hip/hip_runtime.h>
#include <math.h>

typedef __bf16 bf16;
typedef bf16 bf16x8 __attribute__((ext_vector_type(8)));
typedef bf16 bf16x4 __attribute__((ext_vector_type(4)));
typedef float f32x4 __attribute__((ext_vector_type(4)));
typedef unsigned int uint32;

#define B_   2
#define S_   2048
#define H_   2048
#define NH_  16
#define NKV_ 4
#define HD_  128
#define I_   8192
#define M_   (B_ * S_)   // 4096 token rows

// ---------------------------------------------------------------------------
// async global->LDS, 16B per lane. Dest is wave-uniform base + lane*16.
// ---------------------------------------------------------------------------
typedef __attribute__((address_space(3))) void       lds_void;
typedef __attribute__((address_space(1))) const void gbl_void;

__device__ __forceinline__ void async16(const void* g, void* l) {
  __builtin_amdgcn_global_load_lds((gbl_void*)g, (lds_void*)l, 16, 0, 0);
}

// ---------------------------------------------------------------------------
// Dtype probe: raw inputs fp32 vs bf16 (verified: fp32 on this harness).
// ---------------------------------------------------------------------------
__global__ void probe_k(const uint32* __restrict__ x, int* __restrict__ flag) {
  const int lane = threadIdx.x;
  const uint32 u = x[lane];
  float blo = fabsf(__uint_as_float(u << 16));
  float bhi = fabsf(__uint_as_float(u & 0xffff0000u));
  float fv  = fabsf(__uint_as_float(u));
  if (!(blo < 1e30f)) blo = 3e38f;
  if (!(bhi < 1e30f)) bhi = 3e38f;
  if (!(fv  < 1e30f)) fv  = 3e38f;
  float mb = fmaxf(blo, bhi);
  float mf = fv;
#pragma unroll
  for (int off = 1; off < 64; off <<= 1) {
    mb = fmaxf(mb, __shfl_xor(mb, off, 64));
    mf = fmaxf(mf, __shfl_xor(mf, off, 64));
  }
  if (lane == 0) *flag = (mf < mb) ? 1 : 0;
}

// ---------------------------------------------------------------------------
// RMSNorm over H=2048 per row -> bf16 out.
// ---------------------------------------------------------------------------
template <bool INRAW>
__global__ __launch_bounds__(256) void rmsnorm_k(const void* __restrict__ xin,
                                                 const void* __restrict__ w,
                                                 bf16* __restrict__ out,
                                                 const int* __restrict__ dtp) {
  const int f    = *dtp;
  const int row  = blockIdx.x;
  const int tid  = threadIdx.x;
  const int base = row * H_ + tid * 8;

  float v[8];
  if (INRAW && f) {
    const float* xf = (const float*)xin + base;
    f32x4 a = *(const f32x4*)xf, b = *(const f32x4*)(xf + 4);
#pragma unroll
    for (int i = 0; i < 4; ++i) { v[i] = a[i]; v[4 + i] = b[i]; }
  } else {
    bf16x8 t = *(const bf16x8*)((const bf16*)xin + base);
#pragma unroll
    for (int i = 0; i < 8; ++i) v[i] = (float)t[i];
  }

  float ss = 0.f;
#pragma unroll
  for (int i = 0; i < 8; ++i) ss += v[i] * v[i];
#pragma unroll
  for (int off = 1; off < 64; off <<= 1) ss += __shfl_xor(ss, off, 64);

  __shared__ float red[4];
  if ((tid & 63) == 0) red[tid >> 6] = ss;
  __syncthreads();
  ss = red[0] + red[1] + red[2] + red[3];

  const float scale = rsqrtf(ss * (1.0f / H_) + 1e-6f);
  float wv[8];
  if (f) {
    const float* wf = (const float*)w + tid * 8;
    f32x4 a = *(const f32x4*)wf, b = *(const f32x4*)(wf + 4);
#pragma unroll
    for (int i = 0; i < 4; ++i) { wv[i] = a[i]; wv[4 + i] = b[i]; }
  } else {
    bf16x8 t = *(const bf16x8*)((const bf16*)w + tid * 8);
#pragma unroll
    for (int i = 0; i < 8; ++i) wv[i] = (float)t[i];
  }
  bf16x8 o;
#pragma unroll
  for (int i = 0; i < 8; ++i) o[i] = (bf16)(wv[i] * (v[i] * scale));
  *(bf16x8*)(out + base) = o;
}

// ---------------------------------------------------------------------------
// Weight convert+transpose: W (raw [K,N], fp32 or bf16 per dtp) -> bf16 Wt [N,K].
// ---------------------------------------------------------------------------
__global__ __launch_bounds__(256) void convert_wt(const void* __restrict__ W,
                                                  bf16* __restrict__ Wt,
                                                  const int K, const int N,
                                                  const int* __restrict__ dtp) {
  __shared__ bf16 sT[64][72];
  const int f   = *dtp;
  const int tid = threadIdx.x;
  const int k0  = blockIdx.y * 64;
  const int n0  = blockIdx.x * 64;
  if (f) {
#pragma unroll
    for (int p = 0; p < 4; ++p) {
      const int g  = tid + p * 256;
      const int r  = g >> 4;
      const int c4 = (g & 15) * 4;
      f32x4 v = *(const f32x4*)((const float*)W + (size_t)(k0 + r) * N + n0 + c4);
#pragma unroll
      for (int u = 0; u < 4; ++u) sT[c4 + u][r] = (bf16)v[u];
    }
  } else {
#pragma unroll
    for (int p = 0; p < 2; ++p) {
      const int g  = tid + p * 256;
      const int r  = g >> 3;
      const int c8 = (g & 7) * 8;
      bf16x8 v = *(const bf16x8*)((const bf16*)W + (size_t)(k0 + r) * N + n0 + c8);
#pragma unroll
      for (int u = 0; u < 8; ++u) sT[c8 + u][r] = v[u];
    }
  }
  __syncthreads();
#pragma unroll
  for (int p = 0; p < 2; ++p) {
    const int g  = tid + p * 256;
    const int n  = g >> 3;
    const int k8 = (g & 7) * 8;
    bf16x8 ov;
#pragma unroll
    for (int u = 0; u < 8; ++u) ov[u] = sT[n][k8 + u];
    *(bf16x8*)(Wt + (size_t)(n0 + n) * K + k0 + k8) = ov;
  }
}

// ---------------------------------------------------------------------------
// Split-K combine: C = epilogue(p0 + p1, aux). Vectorized x4.
// ---------------------------------------------------------------------------
template <int EPI, bool AUXRAW, bool CRAW>
__global__ __launch_bounds__(256) void combine_k(const float* __restrict__ p0,
                                                 const float* __restrict__ p1,
                                                 const void* __restrict__ aux,
                                                 void* __restrict__ C,
                                                 const size_t total,
                                                 const int* __restrict__ dtp) {
  const int f = *dtp;
  const size_t i = ((size_t)blockIdx.x * 256 + threadIdx.x) * 4;
  if (i >= total) return;
  f32x4 a = *(const f32x4*)(p0 + i);
  f32x4 b = *(const f32x4*)(p1 + i);
  float av4[4];
  if (EPI != 0) {
    if (AUXRAW && f) {
      f32x4 t = *(const f32x4*)((const float*)aux + i);
#pragma unroll
      for (int u = 0; u < 4; ++u) av4[u] = t[u];
    } else {
      bf16x4 t = *(const bf16x4*)((const bf16*)aux + i);
#pragma unroll
      for (int u = 0; u < 4; ++u) av4[u] = (float)t[u];
    }
  }
  float o[4];
#pragma unroll
  for (int u = 0; u < 4; ++u) {
    const float val = a[u] + b[u];
    if (EPI == 0) o[u] = val;
    else if (EPI == 1) o[u] = val + av4[u];
    else {
      const float sg = av4[u] / (1.f + __expf(-av4[u]));
      o[u] = sg * val;
    }
  }
  if (CRAW && f) {
    f32x4 ov; 
#pragma unroll
    for (int u = 0; u < 4; ++u) ov[u] = o[u];
    *(f32x4*)((float*)C + i) = ov;
  } else {
    bf16x4 ov;
#pragma unroll
    for (int u = 0; u < 4; ++u) ov[u] = (bf16)o[u];
    *(bf16x4*)((bf16*)C + i) = ov;
  }
}

// ---------------------------------------------------------------------------
// 256x256 8-phase GEMM (m201 template): C[M,N] = A[M,:] @ Bt[N,:]^T over a
// K-range. lda = leading dim (elements); loop runs K elements starting at
// blockIdx.z*K (split-K). EPI: 0 plain bf16; 1 acc+aux; 2 silu(aux)*acc;
// 3 fp32 partial to C + z*M*N (split-K). Counted vmcnt(6), setprio, swizzle.
// VERIFIED schedule (round 3, 1216us) — do not reorder without race-screen.
// ---------------------------------------------------------------------------
#define BARX()  __builtin_amdgcn_s_barrier()
#define LGKM0() do { asm volatile("s_waitcnt lgkmcnt(0)" ::: "memory");       \
                     __builtin_amdgcn_sched_barrier(0); } while (0)
#define VMW6()  asm volatile("s_waitcnt vmcnt(6)" ::: "memory")

template <int EPI, bool AUXRAW, bool CRAW>
__global__ __launch_bounds__(512, 2) void gemm8_k(const bf16* __restrict__ A,
                                                  const bf16* __restrict__ Bt,
                                                  void* __restrict__ C,
                                                  const void* __restrict__ aux,
                                                  const int M, const int N,
                                                  const int K, const int lda,
                                                  const int* __restrict__ dtp) {
  __shared__ __align__(16) bf16 sA[2][256][64];   // 64 KiB
  __shared__ __align__(16) bf16 sB[2][256][64];   // 64 KiB

  const int f    = *dtp;
  const int tid  = threadIdx.x;
  const int lane = tid & 63;
  const int wave = tid >> 6;
  const int wr   = wave >> 2;    // 0..1
  const int wc   = wave & 3;     // 0..3
  const int l15  = lane & 15;
  const int quad = lane >> 4;

  // XCD-aware bijective swizzle (per z-slice; all grids used are %8==0)
  const int gx  = gridDim.x;
  const int nwg = gx * gridDim.y;
  int bid = blockIdx.y * gx + blockIdx.x;
  if ((nwg & 7) == 0) bid = (bid & 7) * (nwg >> 3) + (bid >> 3);
  const int row0 = (bid / gx) * 256;
  const int col0 = (bid % gx) * 256;
  const int koff = blockIdx.z * K;

  const int NT = K >> 6;   // K-tiles of 64

  // ---- fragment-read addressing (swizzled) ----
  const int swo = (l15 & 7) << 4;
  const int cb0 = (quad * 16) ^ swo;
  const int cb1 = (64 + quad * 16) ^ swo;
  char* sAc = (char*)&sA[0][0][0];
  char* sBc = (char*)&sB[0][0][0];

  // ---- staging source (inverse-swizzled global addr, linear LDS dest) ----
  const int d0   = tid * 16;
  const int d1   = 8192 + tid * 16;
  const int p0   = d0 ^ (((d0 >> 7) & 7) << 4);
  const int p1   = d1 ^ (((d1 >> 7) & 7) << 4);
  const int rg0  = p0 >> 7, cbs0 = p0 & 127;
  const int rg1  = p1 >> 7, cbs1 = p1 & 127;
  const size_t LD2 = (size_t)lda * 2;
  const char* gA = (const char*)A  + (size_t)row0 * LD2 + (size_t)koff * 2;
  const char* gB = (const char*)Bt + (size_t)col0 * LD2 + (size_t)koff * 2;

#define STAGE8(gbase, sbase, s, h, t) do {                                     \
    const int tt_ = ((t) < NT) ? (t) : ((t) - NT);                             \
    const size_t go_ = (size_t)tt_ * 128;                                      \
    async16(gbase + (size_t)((h) * 128 + rg0) * LD2 + go_ + cbs0,              \
            (sbase) + (s) * 32768 + (h) * 16384 + tid * 16);                   \
    async16(gbase + (size_t)((h) * 128 + rg1) * LD2 + go_ + cbs1,              \
            (sbase) + (s) * 32768 + (h) * 16384 + 8192 + tid * 16);            \
  } while (0)
#define STA(s, h, t) STAGE8(gA, sAc, s, h, t)
#define STB(s, h, t) STAGE8(gB, sBc, s, h, t)

  bf16x8 af[4][2], bfr[2][2];
  f32x4 acc[8][4];
#pragma unroll
  for (int m = 0; m < 8; ++m)
#pragma unroll
    for (int n = 0; n < 4; ++n)
#pragma unroll
      for (int r = 0; r < 4; ++r) acc[m][n][r] = 0.f;

#define LDA8(s, mh) do {                                                       \
    _Pragma("unroll")                                                          \
    for (int mi = 0; mi < 4; ++mi) {                                           \
      const int rb = ((mh) * 128 + wr * 64 + mi * 16 + l15) * 128;             \
      af[mi][0] = *(const bf16x8*)(sAc + (s) * 32768 + rb + cb0);              \
      af[mi][1] = *(const bf16x8*)(sAc + (s) * 32768 + rb + cb1);              \
    }                                                                          \
  } while (0)

#define LDB8(s, nh) do {                                                       \
    _Pragma("unroll")                                                          \
    for (int ni = 0; ni < 2; ++ni) {                                           \
      const int rb = ((nh) * 128 + wc * 32 + ni * 16 + l15) * 128;             \
      bfr[ni][0] = *(const bf16x8*)(sBc + (s) * 32768 + rb + cb0);             \
      bfr[ni][1] = *(const bf16x8*)(sBc + (s) * 32768 + rb + cb1);             \
    }                                                                          \
  } while (0)

#define MFMA16(mh, nh) do {                                                    \
    __builtin_amdgcn_s_setprio(1);                                             \
    _Pragma("unroll")                                                          \
    for (int mi = 0; mi < 4; ++mi)                                             \
      _Pragma("unroll")                                                        \
      for (int ni = 0; ni < 2; ++ni) {                                         \
        acc[(mh)*4+mi][(nh)*2+ni] = __builtin_amdgcn_mfma_f32_16x16x32_bf16(   \
            af[mi][0], bfr[ni][0], acc[(mh)*4+mi][(nh)*2+ni], 0, 0, 0);        \
        acc[(mh)*4+mi][(nh)*2+ni] = __builtin_amdgcn_mfma_f32_16x16x32_bf16(   \
            af[mi][1], bfr[ni][1], acc[(mh)*4+mi][(nh)*2+ni], 0, 0, 0);        \
      }                                                                        \
    __builtin_amdgcn_s_setprio(0);                                             \
  } while (0)

  // ---- prologue: tile0 full + 3 halves of tile1; tile0 landed ----
  STA(0, 0, 0); STA(0, 1, 0); STB(0, 0, 0); STB(0, 1, 0);
  STA(1, 0, 1); STA(1, 1, 1); STB(1, 0, 1);
  VMW6();
  BARX();

#pragma unroll 1
  for (int T = 0; T < NT; T += 2) {
    // ph1: tile T quad(0,0); stage hB1(T+1)->buf1
    LDA8(0, 0); LDB8(0, 0);
    STB(1, 1, T + 1);
    BARX(); LGKM0(); MFMA16(0, 0); BARX();
    // ph2: quad(0,1); stage hA0(T+2)->buf0
    LDB8(0, 1);
    STA(0, 0, T + 2);
    BARX(); LGKM0(); MFMA16(0, 1); BARX();
    // ph3: quad(1,0)
    LDA8(0, 1); LDB8(0, 0);
    BARX(); LGKM0(); MFMA16(1, 0); BARX();
    // ph4: quad(1,1); stage hA1,hB0(T+2); vmcnt(6) -> tile T+1 landed
    LDB8(0, 1);
    STA(0, 1, T + 2); STB(0, 0, T + 2);
    BARX(); LGKM0(); MFMA16(1, 1); VMW6(); BARX();
    // ph5: tile T+1 quad(0,0); stage hB1(T+2)->buf0
    LDA8(1, 0); LDB8(1, 0);
    STB(0, 1, T + 2);
    BARX(); LGKM0(); MFMA16(0, 0); BARX();
    // ph6: quad(0,1); stage hA0(T+3)->buf1
    LDB8(1, 1);
    STA(1, 0, T + 3);
    BARX(); LGKM0(); MFMA16(0, 1); BARX();
    // ph7: quad(1,0)
    LDA8(1, 1); LDB8(1, 0);
    BARX(); LGKM0(); MFMA16(1, 0); BARX();
    // ph8: quad(1,1); stage hA1,hB0(T+3); vmcnt(6) -> tile T+2 landed
    LDB8(1, 1);
    STA(1, 1, T + 3); STB(1, 0, T + 3);
    BARX(); LGKM0(); MFMA16(1, 1); VMW6(); BARX();
  }
  asm volatile("s_waitcnt vmcnt(0)" ::: "memory");

  // ---- epilogue ----
  float* P = (EPI == 3)
      ? (float*)C + (size_t)blockIdx.z * ((size_t)M * N) : nullptr;
#pragma unroll
  for (int m = 0; m < 8; ++m) {
#pragma unroll
    for (int n = 0; n < 4; ++n) {
#pragma unroll
      for (int r = 0; r < 4; ++r) {
        const int row = row0 + (m >> 2) * 128 + wr * 64 + (m & 3) * 16 + quad * 4 + r;
        const int col = col0 + (n >> 1) * 128 + wc * 32 + (n & 1) * 16 + l15;
        const size_t idx = (size_t)row * N + col;
        const float val  = acc[m][n][r];
        if (EPI == 3) {
          P[idx] = val;
        } else {
          float outv;
          if (EPI == 0) {
            outv = val;
          } else {
            const float av = (AUXRAW && f) ? ((const float*)aux)[idx]
                                           : (float)((const bf16*)aux)[idx];
            if (EPI == 1) {
              outv = val + av;
            } else {
              const float sg = av / (1.f + __expf(-av));
              outv = sg * val;
            }
          }
          if (CRAW && f) ((float*)C)[idx] = outv;
          else           ((bf16*)C)[idx]  = (bf16)outv;
        }
      }
    }
  }
#undef STAGE8
#undef STA
#undef STB
#undef LDA8
#undef LDB8
#undef MFMA16
}

// ---------------------------------------------------------------------------
// 2-phase 128x128 GEMM (verified m97 structure). lda/split-K like gemm8_k.
// EPI 3 = fp32 partial to C + z*M*N.
// ---------------------------------------------------------------------------
template <int EPI, bool AUXRAW, bool CRAW>
__global__ __launch_bounds__(256) void gemm_bt_k(const bf16* __restrict__ A,
                                                 const bf16* __restrict__ Bt,
                                                 void* __restrict__ C,
                                                 const void* __restrict__ aux,
                                                 const int M, const int N,
                                                 const int K, const int lda,
                                                 const int* __restrict__ dtp) {
  __shared__ __align__(16) bf16 sA[128][32];
  __shared__ __align__(16) bf16 sB[128][32];

  const int f    = *dtp;
  const int tid  = threadIdx.x;
  const int lane = tid & 63;
  const int wave = tid >> 6;
  const int wm   = (wave >> 1) * 64;
  const int wn   = (wave & 1) * 64;
  const int row0 = blockIdx.y * 128;
  const int col0 = blockIdx.x * 128;
  const int koff = blockIdx.z * K;
  const int l15  = lane & 15;
  const int quad = lane >> 4;

  f32x4 acc[4][4];
#pragma unroll
  for (int i = 0; i < 4; ++i)
#pragma unroll
    for (int j = 0; j < 4; ++j)
#pragma unroll
      for (int r = 0; r < 4; ++r) acc[i][j][r] = 0.f;

  const int o  = tid * 16;
  const int r0 = o >> 6;
  const int ib = o & 63;

  const char* gA0 = (const char*)(A  + (size_t)(row0 + r0)      * lda + koff) + ib;
  const char* gA1 = (const char*)(A  + (size_t)(row0 + 64 + r0) * lda + koff) + ib;
  const char* gB0 = (const char*)(Bt + (size_t)(col0 + r0)      * lda + koff) + ib;
  const char* gB1 = (const char*)(Bt + (size_t)(col0 + 64 + r0) * lda + koff) + ib;
  char* lA = (char*)(&sA[0][0]) + wave * 1024;
  char* lB = (char*)(&sB[0][0]) + wave * 1024;

  for (int k0 = 0; k0 < K; k0 += 32) {
    async16(gA0, lA);
    async16(gA1, lA + 4096);
    async16(gB0, lB);
    async16(gB1, lB + 4096);
    gA0 += 64; gA1 += 64; gB0 += 64; gB1 += 64;
    __syncthreads();

    bf16x8 af[4], bfr[4];
#pragma unroll
    for (int i = 0; i < 4; ++i)
      af[i] = *(const bf16x8*)(&sA[wm + i * 16 + l15][quad * 8]);
#pragma unroll
    for (int j = 0; j < 4; ++j)
      bfr[j] = *(const bf16x8*)(&sB[wn + j * 16 + l15][quad * 8]);
#pragma unroll
    for (int i = 0; i < 4; ++i)
#pragma unroll
      for (int j = 0; j < 4; ++j)
        acc[i][j] = __builtin_amdgcn_mfma_f32_16x16x32_bf16(af[i], bfr[j],
                                                            acc[i][j], 0, 0, 0);
    __syncthreads();
  }

  float* P = (EPI == 3)
      ? (float*)C + (size_t)blockIdx.z * ((size_t)M * N) : nullptr;
#pragma unroll
  for (int i = 0; i < 4; ++i) {
#pragma unroll
    for (int j = 0; j < 4; ++j) {
#pragma unroll
      for (int r = 0; r < 4; ++r) {
        const int row    = row0 + wm + i * 16 + quad * 4 + r;
        const int col    = col0 + wn + j * 16 + l15;
        const size_t idx = (size_t)row * N + col;
        const float val  = acc[i][j][r];
        if (EPI == 3) {
          P[idx] = val;
        } else {
          float outv;
          if (EPI == 0) {
            outv = val;
          } else {
            const float av = (AUXRAW && f) ? ((const float*)aux)[idx]
                                           : (float)((const bf16*)aux)[idx];
            if (EPI == 1) {
              outv = val + av;
            } else {
              const float sg = av / (1.f + __expf(-av));
              outv = sg * val;
            }
          }
          if (CRAW && f) ((float*)C)[idx] = outv;
          else           ((bf16*)C)[idx]  = (bf16)outv;
        }
      }
    }
  }
}

// ---------------------------------------------------------------------------
// Legacy GEMM (fallback when workspace can't hold the B^T scratch).
// ---------------------------------------------------------------------------
template <int EPI, bool AUXRAW, bool CRAW>
__global__ __launch_bounds__(256) void gemm_k(const bf16* __restrict__ A,
                                              const void* __restrict__ Bm,
                                              void* __restrict__ C,
                                              const void* __restrict__ aux,
                                              const int M, const int N, const int K,
                                              const int* __restrict__ dtp) {
  __shared__ __align__(16) bf16 sA[128][40];
  __shared__ __align__(16) bf16 sB[128][40];

  const int f    = *dtp;
  const int tid  = threadIdx.x;
  const int lane = tid & 63;
  const int wave = tid >> 6;
  const int wm   = (wave >> 1) * 64;
  const int wn   = (wave & 1) * 64;
  const int row0 = blockIdx.y * 128;
  const int col0 = blockIdx.x * 128;
  const int l15  = lane & 15;
  const int quad = lane >> 4;

  f32x4 acc[4][4];
#pragma unroll
  for (int i = 0; i < 4; ++i)
#pragma unroll
    for (int j = 0; j < 4; ++j)
#pragma unroll
      for (int r = 0; r < 4; ++r) acc[i][j][r] = 0.f;

  for (int k0 = 0; k0 < K; k0 += 32) {
#pragma unroll
    for (int pass = 0; pass < 2; ++pass) {
      const int g  = tid + pass * 256;
      const int ar = g >> 2, ac = (g & 3) * 8;
      *(bf16x8*)(&sA[ar][ac]) =
          *(const bf16x8*)(A + (size_t)(row0 + ar) * K + k0 + ac);
      const int br = g >> 4, bc = (g & 15) * 8;
      const size_t boff = (size_t)(k0 + br) * N + col0 + bc;
      bf16x8 bv;
      if (f) {
        const float* bp = (const float*)Bm + boff;
        f32x4 lo = *(const f32x4*)bp, hi = *(const f32x4*)(bp + 4);
#pragma unroll
        for (int u = 0; u < 8; ++u) bv[u] = (bf16)(u < 4 ? lo[u] : hi[u - 4]);
      } else {
        bv = *(const bf16x8*)((const bf16*)Bm + boff);
      }
#pragma unroll
      for (int u = 0; u < 8; ++u) sB[bc + u][br] = bv[u];
    }
    __syncthreads();

    bf16x8 af[4], bfr[4];
#pragma unroll
    for (int i = 0; i < 4; ++i)
      af[i] = *(const bf16x8*)(&sA[wm + i * 16 + l15][quad * 8]);
#pragma unroll
    for (int j = 0; j < 4; ++j)
      bfr[j] = *(const bf16x8*)(&sB[wn + j * 16 + l15][quad * 8]);
#pragma unroll
    for (int i = 0; i < 4; ++i)
#pragma unroll
      for (int j = 0; j < 4; ++j)
        acc[i][j] = __builtin_amdgcn_mfma_f32_16x16x32_bf16(af[i], bfr[j],
                                                            acc[i][j], 0, 0, 0);
    __syncthreads();
  }

#pragma unroll
  for (int i = 0; i < 4; ++i) {
#pragma unroll
    for (int j = 0; j < 4; ++j) {
#pragma unroll
      for (int r = 0; r < 4; ++r) {
        const int row    = row0 + wm + i * 16 + quad * 4 + r;
        const int col    = col0 + wn + j * 16 + l15;
        const size_t idx = (size_t)row * N + col;
        const float val  = acc[i][j][r];
        float outv;
        if (EPI == 0) {
          outv = val;
        } else {
          const float av = (AUXRAW && f) ? ((const float*)aux)[idx]
                                         : (float)((const bf16*)aux)[idx];
          if (EPI == 1) {
            outv = val + av;
          } else {
            const float sg = av / (1.f + __expf(-av));
            outv = sg * val;
          }
        }
        if (CRAW && f) ((float*)C)[idx] = outv;
        else           ((bf16*)C)[idx]  = (bf16)outv;
      }
    }
  }
}

// ---------------------------------------------------------------------------
// RoPE + QK-RMSNorm, in place on q [M,2048] and k [M,512].
// ---------------------------------------------------------------------------
__global__ __launch_bounds__(256) void rope_norm_k(bf16* __restrict__ q,
                                                   bf16* __restrict__ k,
                                                   const void* __restrict__ qw,
                                                   const void* __restrict__ kw,
                                                   const int* __restrict__ dtp) {
  const int f    = *dtp;
  const int task = blockIdx.x * 4 + (threadIdx.x >> 6);
  const int lane = threadIdx.x & 63;
  const int row  = task / 20;
  const int hh   = task - row * 20;

  bf16* p;
  const void* w;
  if (hh < NH_) { p = q + (size_t)row * 2048 + hh * 128;        w = qw; }
  else          { p = k + (size_t)row * 512 + (hh - NH_) * 128; w = kw; }

  const float pos = (float)(row & (S_ - 1));
  const float inv = powf(10000.f, -(float)lane * (1.f / 64.f));
  float sn, cs;
  sincosf(pos * inv, &sn, &cs);

  const float x0 = (float)p[lane], x1 = (float)p[lane + 64];
  const float r0 = x0 * cs - x1 * sn;
  const float r1 = x1 * cs + x0 * sn;

  float ss = r0 * r0 + r1 * r1;
#pragma unroll
  for (int off = 1; off < 64; off <<= 1) ss += __shfl_xor(ss, off, 64);
  const float scale = rsqrtf(ss * (1.f / 128.f) + 1e-6f);

  const float w0 = f ? ((const float*)w)[lane]      : (float)((const bf16*)w)[lane];
  const float w1 = f ? ((const float*)w)[lane + 64] : (float)((const bf16*)w)[lane + 64];
  p[lane]      = (bf16)(w0 * (r0 * scale));
  p[lane + 64] = (bf16)(w1 * (r1 * scale));
}

// ---------------------------------------------------------------------------
// V transpose: v [M,512] -> vt [B][512][S].
// ---------------------------------------------------------------------------
__global__ __launch_bounds__(256) void transpose_v(const bf16* __restrict__ v,
                                                   bf16* __restrict__ vt) {
  __shared__ bf16 sT[64][68];
  const int tid = threadIdx.x;
  const int r0  = blockIdx.y * 64;
  const int c0  = blockIdx.x * 64;
  const int b   = r0 >> 11;
  const int s0  = r0 & 2047;
#pragma unroll
  for (int p = 0; p < 2; ++p) {
    const int g   = tid + p * 256;
    const int row = g >> 3;
    const int c8  = (g & 7) * 8;
    bf16x8 tv = *(const bf16x8*)(v + (size_t)(r0 + row) * 512 + c0 + c8);
#pragma unroll
    for (int u = 0; u < 8; ++u) sT[c8 + u][row] = tv[u];
  }
  __syncthreads();
#pragma unroll
  for (int p = 0; p < 2; ++p) {
    const int g  = tid + p * 256;
    const int oc = g >> 3;
    const int s8 = (g & 7) * 8;
    bf16x8 ov;
#pragma unroll
    for (int u = 0; u < 8; ++u) ov[u] = sT[oc][s8 + u];
    *(bf16x8*)(vt + ((size_t)(b * 512 + c0 + oc)) * 2048 + s0 + s8) = ov;
  }
}

// ---------------------------------------------------------------------------
// MFMA flash attention (causal, GQA). Unchanged from verified kernel.
// ---------------------------------------------------------------------------
__global__ __launch_bounds__(256) void attn_mfma(const bf16* __restrict__ q,
                                                 const bf16* __restrict__ k,
                                                 const bf16* __restrict__ vt,
                                                 bf16* __restrict__ ctx) {
  __shared__ __align__(16) bf16 sK[64][136];
  __shared__ __align__(16) bf16 sV[128][72];
  __shared__ __align__(16) bf16 sP[4][16][72];

  const int tid  = threadIdx.x;
  const int lane = tid & 63;
  const int wave = tid >> 6;
  const int l15  = lane & 15;
  const int quad = lane >> 4;

  const int bid = blockIdx.x;
  const int i7  = bid & 127;
  const int qt  = (i7 & 1) ? (127 - (i7 >> 1)) : (i7 >> 1);
  const int kvh = (bid >> 7) & 3;
  const int b   = bid >> 9;
  const int q0  = qt * 16;
  const int h   = kvh * 4 + wave;

  bf16x8 qf[4];
  {
    const bf16* qp = q + (size_t)(b * S_ + q0 + l15) * 2048 + h * 128 + quad * 8;
#pragma unroll
    for (int c = 0; c < 4; ++c) qf[c] = *(const bf16x8*)(qp + c * 32);
  }

  float m4[4], l4[4];
  f32x4 of[8];
#pragma unroll
  for (int r = 0; r < 4; ++r) { m4[r] = -1e30f; l4[r] = 0.f; }
#pragma unroll
  for (int dg = 0; dg < 8; ++dg)
#pragma unroll
    for (int r = 0; r < 4; ++r) of[dg][r] = 0.f;

  const int ntiles = (q0 + 16 + 63) >> 6;
  const bf16* kbase = k + (size_t)b * S_ * 512 + kvh * 128;
  const bf16* vbase = vt + (size_t)(b * 512 + kvh * 128) * 2048;
  const float sc = 0.088388347648318447f;

  for (int t = 0; t < ntiles; ++t) {
    const int j0 = t << 6;
#pragma unroll
    for (int p = 0; p < 4; ++p) {
      const int g   = tid + p * 256;
      const int dc  = g & 15;
      const int key = g >> 4;
      *(bf16x8*)(&sK[key][dc * 8]) =
          *(const bf16x8*)(kbase + (size_t)(j0 + key) * 512 + dc * 8);
    }
#pragma unroll
    for (int p = 0; p < 4; ++p) {
      const int g   = tid + p * 256;
      const int dim = g >> 3;
      const int k8  = (g & 7) * 8;
      *(bf16x8*)(&sV[dim][k8]) =
          *(const bf16x8*)(vbase + (size_t)dim * 2048 + j0 + k8);
    }
    __syncthreads();

    f32x4 sa[4];
#pragma unroll
    for (int g = 0; g < 4; ++g)
#pragma unroll
      for (int r = 0; r < 4; ++r) sa[g][r] = 0.f;
#pragma unroll
    for (int g = 0; g < 4; ++g)
#pragma unroll
      for (int c = 0; c < 4; ++c) {
        bf16x8 kf = *(const bf16x8*)(&sK[g * 16 + l15][c * 32 + quad * 8]);
        sa[g] = __builtin_amdgcn_mfma_f32_16x16x32_bf16(qf[c], kf, sa[g], 0, 0, 0);
      }

    float s[4][4];
    const bool mask = (t == ntiles - 1);
#pragma unroll
    for (int g = 0; g < 4; ++g)
#pragma unroll
      for (int r = 0; r < 4; ++r) {
        float x = sa[g][r] * sc;
        if (mask && (j0 + g * 16 + l15 > q0 + quad * 4 + r)) x = -1e30f;
        s[g][r] = x;
      }

    float al[4];
#pragma unroll
    for (int r = 0; r < 4; ++r) {
      float rm = fmaxf(fmaxf(s[0][r], s[1][r]), fmaxf(s[2][r], s[3][r]));
#pragma unroll
      for (int off = 1; off < 16; off <<= 1) rm = fmaxf(rm, __shfl_xor(rm, off, 64));
      const float mn = fmaxf(m4[r], rm);
      al[r] = __expf(m4[r] - mn);
      float rs = 0.f;
#pragma unroll
      for (int g = 0; g < 4; ++g) { s[g][r] = __expf(s[g][r] - mn); rs += s[g][r]; }
#pragma unroll
      for (int off = 1; off < 16; off <<= 1) rs += __shfl_xor(rs, off, 64);
      l4[r] = l4[r] * al[r] + rs;
      m4[r] = mn;
    }
#pragma unroll
    for (int dg = 0; dg < 8; ++dg)
#pragma unroll
      for (int r = 0; r < 4; ++r) of[dg][r] *= al[r];

#pragma unroll
    for (int g = 0; g < 4; ++g)
#pragma unroll
      for (int r = 0; r < 4; ++r)
        sP[wave][quad * 4 + r][g * 16 + l15] = (bf16)s[g][r];
    bf16x8 pf[2];
#pragma unroll
    for (int c = 0; c < 2; ++c)
      pf[c] = *(const bf16x8*)(&sP[wave][l15][c * 32 + quad * 8]);

#pragma unroll
    for (int c = 0; c < 2; ++c)
#pragma unroll
      for (int dg = 0; dg < 8; ++dg) {
        bf16x8 vf = *(const bf16x8*)(&sV[dg * 16 + l15][c * 32 + quad * 8]);
        of[dg] = __builtin_amdgcn_mfma_f32_16x16x32_bf16(pf[c], vf, of[dg], 0, 0, 0);
      }
    __syncthreads();
  }

  bf16* op = ctx + (size_t)(b * S_ + q0) * 2048 + h * 128;
#pragma unroll
  for (int r = 0; r < 4; ++r) {
    const float rl = 1.f / l4[r];
    const int row  = quad * 4 + r;
#pragma unroll
    for (int dg = 0; dg < 8; ++dg)
      op[(size_t)row * 2048 + dg * 16 + l15] = (bf16)(of[dg][r] * rl);
  }
}

// ---------------------------------------------------------------------------
// Workspace (bf16 elements, after 16-byte flag slot):
//   slotA [8.4M] slotB [8.4M] slotC [2.1M] slotD [2.1M] slotE [33.6M]
//   wT [16.8M]  (B^T scratch, tier >= 1)
//   slotP [2 x 8.4M floats = 67MB]  (split-K partials, tier 2 only)
// ---------------------------------------------------------------------------
extern "C" void kernel_launch(void* const* d_in, const int* in_sizes, int n_in,
                              void* d_out, int out_size, void* d_ws, size_t ws_size,
                              hipStream_t stream) {
  (void)in_sizes; (void)n_in; (void)out_size;

  const void* hidden = d_in[0];
  const void* ln1 = d_in[3];
  const void* Wq  = d_in[4];
  const void* Wk  = d_in[5];
  const void* Wv  = d_in[6];
  const void* Wo  = d_in[7];
  const void* qn  = d_in[8];
  const void* kn  = d_in[9];
  const void* ln2 = d_in[10];
  const void* Wg  = d_in[11];
  const void* Wu  = d_in[12];
  const void* Wd  = d_in[13];

  int*  dtp   = (int*)d_ws;
  bf16* slotA = (bf16*)((char*)d_ws + 16);
  bf16* slotB = slotA + (size_t)M_ * 2048;
  bf16* slotC = slotB + (size_t)M_ * 2048;
  bf16* slotD = slotC + (size_t)M_ * 512;
  bf16* slotE = slotD + (size_t)M_ * 512;
  bf16* vT    = slotE;
  bf16* wT    = slotE + (size_t)M_ * 8192;
  float* pP   = (float*)(wT + (size_t)I_ * H_);
  float* pP1  = pP + (size_t)M_ * 2048;

  const size_t need1 = 16 + 2ull * ((size_t)M_ * 2048 * 2 + (size_t)M_ * 512 * 2 +
                                    (size_t)M_ * 8192 + (size_t)I_ * H_);
  const size_t need2 = need1 + 2ull * (size_t)M_ * 2048 * 4;

  probe_k<<<1, 64, 0, stream>>>((const uint32*)hidden, dtp);
  rmsnorm_k<true><<<M_, 256, 0, stream>>>(hidden, ln1, slotA, dtp);

  if (ws_size >= need2) {
    // ---- tier 2: split-K for the N<=2048 GEMMs (full-GPU grids) ----
    convert_wt<<<dim3(32, 32), 256, 0, stream>>>(Wq, wT, 2048, 2048, dtp);
    gemm8_k<3, false, false><<<dim3(8, 16, 2), 512, 0, stream>>>(slotA, wT, pP, nullptr, M_, 2048, 1024, 2048, dtp);
    combine_k<0, false, false><<<(M_ * 2048) / 1024, 256, 0, stream>>>(pP, pP1, nullptr, slotB, (size_t)M_ * 2048, dtp);
    convert_wt<<<dim3(8, 32), 256, 0, stream>>>(Wk, wT, 2048, 512, dtp);
    gemm_bt_k<3, false, false><<<dim3(4, 32, 2), 256, 0, stream>>>(slotA, wT, pP, nullptr, M_, 512, 1024, 2048, dtp);
    combine_k<0, false, false><<<(M_ * 512) / 1024, 256, 0, stream>>>(pP, pP + (size_t)M_ * 512, nullptr, slotC, (size_t)M_ * 512, dtp);
    convert_wt<<<dim3(8, 32), 256, 0, stream>>>(Wv, wT, 2048, 512, dtp);
    gemm_bt_k<3, false, false><<<dim3(4, 32, 2), 256, 0, stream>>>(slotA, wT, pP, nullptr, M_, 512, 1024, 2048, dtp);
    combine_k<0, false, false><<<(M_ * 512) / 1024, 256, 0, stream>>>(pP, pP + (size_t)M_ * 512, nullptr, slotD, (size_t)M_ * 512, dtp);
    transpose_v<<<dim3(8, 64), 256, 0, stream>>>(slotD, vT);
    rope_norm_k<<<(M_ * (NH_ + NKV_)) / 4, 256, 0, stream>>>(slotB, slotC, qn, kn, dtp);
    attn_mfma<<<B_ * NKV_ * (S_ / 16), 256, 0, stream>>>(slotB, slotC, vT, slotA);
    convert_wt<<<dim3(32, 32), 256, 0, stream>>>(Wo, wT, 2048, 2048, dtp);
    gemm8_k<3, false, false><<<dim3(8, 16, 2), 512, 0, stream>>>(slotA, wT, pP, nullptr, M_, 2048, 1024, 2048, dtp);
    combine_k<1, true, false><<<(M_ * 2048) / 1024, 256, 0, stream>>>(pP, pP1, hidden, slotB, (size_t)M_ * 2048, dtp);
    rmsnorm_k<false><<<M_, 256, 0, stream>>>(slotB, ln2, slotA, dtp);
    convert_wt<<<dim3(128, 32), 256, 0, stream>>>(Wg, wT, 2048, 8192, dtp);
    gemm8_k<0, false, false><<<dim3(32, 16), 512, 0, stream>>>(slotA, wT, slotE, nullptr, M_, 8192, 2048, 2048, dtp);
    convert_wt<<<dim3(128, 32), 256, 0, stream>>>(Wu, wT, 2048, 8192, dtp);
    gemm8_k<2, false, false><<<dim3(32, 16), 512, 0, stream>>>(slotA, wT, slotE, slotE, M_, 8192, 2048, 2048, dtp);
    convert_wt<<<dim3(32, 128), 256, 0, stream>>>(Wd, wT, 8192, 2048, dtp);
    gemm8_k<3, false, false><<<dim3(8, 16, 2), 512, 0, stream>>>(slotE, wT, pP, nullptr, M_, 2048, 4096, 8192, dtp);
    combine_k<1, false, true><<<(M_ * 2048) / 1024, 256, 0, stream>>>(pP, pP1, slotB, d_out, (size_t)M_ * 2048, dtp);
  } else if (ws_size >= need1) {
    // ---- tier 1: no split-K scratch ----
    convert_wt<<<dim3(32, 32), 256, 0, stream>>>(Wq, wT, 2048, 2048, dtp);
    gemm8_k<0, false, false><<<dim3(8, 16), 512, 0, stream>>>(slotA, wT, slotB, nullptr, M_, 2048, 2048, 2048, dtp);
    convert_wt<<<dim3(8, 32), 256, 0, stream>>>(Wk, wT, 2048, 512, dtp);
    gemm_bt_k<0, false, false><<<dim3(4, 32), 256, 0, stream>>>(slotA, wT, slotC, nullptr, M_, 512, 2048, 2048, dtp);
    convert_wt<<<dim3(8, 32), 256, 0, stream>>>(Wv, wT, 2048, 512, dtp);
    gemm_bt_k<0, false, false><<<dim3(4, 32), 256, 0, stream>>>(slotA, wT, slotD, nullptr, M_, 512, 2048, 2048, dtp);
    transpose_v<<<dim3(8, 64), 256, 0, stream>>>(slotD, vT);
    rope_norm_k<<<(M_ * (NH_ + NKV_)) / 4, 256, 0, stream>>>(slotB, slotC, qn, kn, dtp);
    attn_mfma<<<B_ * NKV_ * (S_ / 16), 256, 0, stream>>>(slotB, slotC, vT, slotA);
    convert_wt<<<dim3(32, 32), 256, 0, stream>>>(Wo, wT, 2048, 2048, dtp);
    gemm8_k<1, true, false><<<dim3(8, 16), 512, 0, stream>>>(slotA, wT, slotB, hidden, M_, 2048, 2048, 2048, dtp);
    rmsnorm_k<false><<<M_, 256, 0, stream>>>(slotB, ln2, slotA, dtp);
    convert_wt<<<dim3(128, 32), 256, 0, stream>>>(Wg, wT, 2048, 8192, dtp);
    gemm8_k<0, false, false><<<dim3(32, 16), 512, 0, stream>>>(slotA, wT, slotE, nullptr, M_, 8192, 2048, 2048, dtp);
    convert_wt<<<dim3(128, 32), 256, 0, stream>>>(Wu, wT, 2048, 8192, dtp);
    gemm8_k<2, false, false><<<dim3(32, 16), 512, 0, stream>>>(slotA, wT, slotE, slotE, M_, 8192, 2048, 2048, dtp);
    convert_wt<<<dim3(32, 128), 256, 0, stream>>>(Wd, wT, 8192, 2048, dtp);
    gemm8_k<1, false, true><<<dim3(8, 16), 512, 0, stream>>>(slotE, wT, d_out, slotB, M_, 2048, 8192, 8192, dtp);
  } else {
    // ---- fallback: legacy in-GEMM conversion path (verified) ----
    gemm_k<0, false, false><<<dim3(16, 32), 256, 0, stream>>>(slotA, Wq, slotB, nullptr, M_, 2048, 2048, dtp);
    gemm_k<0, false, false><<<dim3(4, 32), 256, 0, stream>>>(slotA, Wk, slotC, nullptr, M_, 512, 2048, dtp);
    gemm_k<0, false, false><<<dim3(4, 32), 256, 0, stream>>>(slotA, Wv, slotD, nullptr, M_, 512, 2048, dtp);
    transpose_v<<<dim3(8, 64), 256, 0, stream>>>(slotD, vT);
    rope_norm_k<<<(M_ * (NH_ + NKV_)) / 4, 256, 0, stream>>>(slotB, slotC, qn, kn, dtp);
    attn_mfma<<<B_ * NKV_ * (S_ / 16), 256, 0, stream>>>(slotB, slotC, vT, slotA);
    gemm_k<1, true, false><<<dim3(16, 32), 256, 0, stream>>>(slotA, Wo, slotB, hidden, M_, 2048, 2048, dtp);
    rmsnorm_k<false><<<M_, 256, 0, stream>>>(slotB, ln2, slotA, dtp);
    gemm_k<0, false, false><<<dim3(64, 32), 256, 0, stream>>>(slotA, Wg, slotE, nullptr, M_, 8192, 2048, dtp);
    gemm_k<2, false, false><<<dim3(64, 32), 256, 0, stream>>>(slotA, Wu, slotE, slotE, M_, 8192, 2048, dtp);
    gemm_k<1, false, true><<<dim3(16, 32), 256, 0, stream>>>(slotE, Wd, d_out, slotB, M_, 2048, 8192, dtp);
  }
}